// Round 7
// baseline (3738.768 us; speedup 1.0000x reference)
//
#include <hip/hip_runtime.h>
#include <hip/hip_cooperative_groups.h>
#include <hip/hip_bf16.h>
#include <math.h>

// V=32000 E=512 H=1024 A=1024 L=2 B=16 T=64 S=64
typedef __bf16 bf16x8 __attribute__((ext_vector_type(8)));
typedef float  f32x4  __attribute__((ext_vector_type(4)));
typedef int    i32x4  __attribute__((ext_vector_type(4)));

#define MFMA16 __builtin_amdgcn_mfma_f32_16x16x32_bf16
#define WAIT_VM0()   { asm volatile("s_waitcnt vmcnt(0)" ::: "memory");   __builtin_amdgcn_sched_barrier(0); }
#define WAIT_LGKM0() { asm volatile("s_waitcnt lgkmcnt(0)" ::: "memory"); __builtin_amdgcn_sched_barrier(0); }

__device__ __forceinline__ float sigm(float x){ return 1.0f/(1.0f+expf(-x)); }
__device__ __forceinline__ f32x4 ld4(const float* p){ return *(const f32x4*)p; }
__device__ __forceinline__ void split2(float x, __bf16* h, __bf16* l){
  __bf16 hh = (__bf16)x; *h = hh; *l = (__bf16)(x - (float)hh);
}

// ======== L2-bypass (device-coherent) access helpers: sc0 sc1 ========
__device__ __forceinline__ bf16x8 ldx4b_bf(const __bf16* p){
  bf16x8 r;
  asm volatile("global_load_dwordx4 %0, %1, off sc0 sc1" : "=v"(r) : "v"(p) : "memory");
  return r;
}
__device__ __forceinline__ float ldfb(const float* p){
  float r;
  asm volatile("global_load_dword %0, %1, off sc0 sc1" : "=v"(r) : "v"(p) : "memory");
  return r;
}
__device__ __forceinline__ void stfb(float* p, float v){
  asm volatile("global_store_dword %0, %1, off sc0 sc1" :: "v"(p), "v"(v) : "memory");
}
__device__ __forceinline__ void stib(int* p, int v){
  asm volatile("global_store_dword %0, %1, off sc0 sc1" :: "v"(p), "v"(v) : "memory");
}
__device__ __forceinline__ void stsb(__bf16* p, __bf16 v){
  unsigned int b = (unsigned int)__builtin_bit_cast(unsigned short, v);
  asm volatile("global_store_short %0, %1, off sc0 sc1" :: "v"(p), "v"(b) : "memory");
}

// ======== decentralized L2-preserving grid barrier ========
// Each block publishes flags[blk]=target (bypass store); wave 0 polls all 256
// flags (one dwordx4/lane) until min >= target. No atomics, no cache nukes.
__device__ __forceinline__ void barrier_dev(int* flags, int blk, int target){
  WAIT_VM0();
  __syncthreads();                 // all waves' bypass stores drained
  int tid = threadIdx.x;
  if(tid == 0) stib(flags + blk, target);
  if(tid < 64){
    const int* p = flags + tid*4;
    for(;;){
      i32x4 v;
      asm volatile("global_load_dwordx4 %0, %1, off sc0 sc1\n\ts_waitcnt vmcnt(0)"
                   : "=v"(v) : "v"(p) : "memory");
      int m01 = v[0] < v[1] ? v[0] : v[1];
      int m23 = v[2] < v[3] ? v[2] : v[3];
      int m = m01 < m23 ? m01 : m23;
      if(__all(m >= target)) break;
      __builtin_amdgcn_s_sleep(4);
    }
  }
  __syncthreads();
}

// ---------- transpose fp32 ----------
__global__ __launch_bounds__(256) void k_transpose(const float* __restrict__ in,
                                                   float* __restrict__ out, int R, int C){
  __shared__ float tile[32][33];
  int c0 = blockIdx.x*32, r0 = blockIdx.y*32;
  int tx = threadIdx.x & 31, ty = threadIdx.x >> 5;
  for(int i=ty;i<32;i+=8) tile[i][tx] = in[(size_t)(r0+i)*C + c0+tx];
  __syncthreads();
  for(int i=ty;i<32;i+=8) out[(size_t)(c0+i)*R + r0+tx] = tile[tx][i];
}

// ---------- gather fp32 ----------
__global__ __launch_bounds__(256) void k_gather(const int* __restrict__ tgt,
                                                const float* __restrict__ emb,
                                                float* __restrict__ emb_tok){
  int m = blockIdx.x;            // m = t*16+b
  int t = m >> 4, b = m & 15;
  int row = tgt[b*64 + t];
  const float* src = emb + (size_t)row*512;
  float* dst = emb_tok + (size_t)m*512;
  for(int e=threadIdx.x;e<512;e+=256) dst[e] = src[e];
}

// ---------- setup GEMM (hi/lo MFMA, fp32-accurate) ----------
__global__ __launch_bounds__(256) void k_gemm_s(
    const float* __restrict__ A, int lda,
    const float* __restrict__ Bt, int ldb,
    const float* __restrict__ bias,
    float* __restrict__ C, int N, int K)
{
  __shared__ __align__(16) __bf16 Ash[128][40];
  __shared__ __align__(16) __bf16 Asl[128][40];
  __shared__ __align__(16) __bf16 Bsh[64][40];
  __shared__ __align__(16) __bf16 Bsl[64][40];
  int tid = threadIdx.x;
  int m0 = blockIdx.x*128, n0 = blockIdx.y*64;
  int lane = tid & 63, wave = tid >> 6;
  int wr = wave >> 1, wc = wave & 1;
  int qq = lane >> 4, rr = lane & 15;
  f32x4 acc[4][2] = {};
  int ar = tid >> 1, ak = (tid & 1)*16;
  int br = tid >> 2, bk = (tid & 3)*8;
  for(int k0=0;k0<K;k0+=32){
    const float* ap = A + (size_t)(m0+ar)*lda + k0 + ak;
    f32x4 a0 = ld4(ap), a1 = ld4(ap+4), a2 = ld4(ap+8), a3 = ld4(ap+12);
    const float* bp = Bt + (size_t)(n0+br)*ldb + k0 + bk;
    f32x4 b0 = ld4(bp), b1 = ld4(bp+4);
    __syncthreads();
    #pragma unroll
    for(int e=0;e<4;++e){
      split2(a0[e], &Ash[ar][ak+e],    &Asl[ar][ak+e]);
      split2(a1[e], &Ash[ar][ak+4+e],  &Asl[ar][ak+4+e]);
      split2(a2[e], &Ash[ar][ak+8+e],  &Asl[ar][ak+8+e]);
      split2(a3[e], &Ash[ar][ak+12+e], &Asl[ar][ak+12+e]);
      split2(b0[e], &Bsh[br][bk+e],    &Bsl[br][bk+e]);
      split2(b1[e], &Bsh[br][bk+4+e],  &Bsl[br][bk+4+e]);
    }
    __syncthreads();
    bf16x8 afh[4], afl[4], bfh[2], bfl[2];
    #pragma unroll
    for(int mi=0;mi<4;++mi){
      afh[mi] = *(const bf16x8*)&Ash[wr*64 + mi*16 + rr][qq*8];
      afl[mi] = *(const bf16x8*)&Asl[wr*64 + mi*16 + rr][qq*8];
    }
    #pragma unroll
    for(int ni=0;ni<2;++ni){
      bfh[ni] = *(const bf16x8*)&Bsh[wc*32 + ni*16 + rr][qq*8];
      bfl[ni] = *(const bf16x8*)&Bsl[wc*32 + ni*16 + rr][qq*8];
    }
    #pragma unroll
    for(int mi=0;mi<4;++mi)
      #pragma unroll
      for(int ni=0;ni<2;++ni){
        acc[mi][ni] = MFMA16(afh[mi], bfh[ni], acc[mi][ni], 0,0,0);
        acc[mi][ni] = MFMA16(afl[mi], bfh[ni], acc[mi][ni], 0,0,0);
        acc[mi][ni] = MFMA16(afh[mi], bfl[ni], acc[mi][ni], 0,0,0);
      }
  }
  #pragma unroll
  for(int mi=0;mi<4;++mi)
    #pragma unroll
    for(int ni=0;ni<2;++ni)
      #pragma unroll
      for(int i=0;i<4;++i){
        int m = m0 + wr*64 + mi*16 + qq*4 + i;
        int n = n0 + wc*32 + ni*16 + rr;
        C[(size_t)m*N + n] = acc[mi][ni][i] + (bias? bias[n] : 0.f);
      }
}

// ---------- pack W[J][1024] fp32 -> MFMA B-frag panels, bf16 hi/lo ----------
__global__ __launch_bounds__(256) void k_pack_w(const float* __restrict__ W,
                                                __bf16* __restrict__ Wp){
  int jt = blockIdx.x, tid = threadIdx.x;
  #pragma unroll
  for(int it=0; it<8; ++it){
    int pos = it*256 + tid;
    int kt = pos>>6, l = pos&63;
    const float* src = W + (size_t)(jt*16 + (l&15))*1024 + kt*32 + (l>>4)*8;
    f32x4 s0 = ld4(src), s1 = ld4(src+4);
    bf16x8 vh, vl;
    #pragma unroll
    for(int e=0;e<4;++e){
      __bf16 h, lo;
      split2(s0[e], &h, &lo); vh[e]   = h; vl[e]   = lo;
      split2(s1[e], &h, &lo); vh[4+e] = h; vl[4+e] = lo;
    }
    __bf16* dst = Wp + ((size_t)(jt*32 + kt))*1024 + l*8;
    *(bf16x8*)dst       = vh;
    *(bf16x8*)(dst+512) = vl;
  }
}

// ---------- pack, reading W transposed ----------
__global__ __launch_bounds__(256) void k_pack_wT(const float* __restrict__ W, int ldw,
                                                 __bf16* __restrict__ Wp){
  int jt = blockIdx.x, tid = threadIdx.x;
  #pragma unroll
  for(int it=0; it<8; ++it){
    int pos = it*256 + tid;
    int kt = pos>>6, l = pos&63;
    int j = jt*16 + (l&15);
    int kbase = kt*32 + (l>>4)*8;
    bf16x8 vh, vl;
    #pragma unroll
    for(int e=0;e<8;++e){
      float x = W[(size_t)(kbase+e)*ldw + j];
      __bf16 h = (__bf16)x;
      vh[e] = h; vl[e] = (__bf16)(x - (float)h);
    }
    __bf16* dst = Wp + ((size_t)(jt*32 + kt))*1024 + l*8;
    *(bf16x8*)dst       = vh;
    *(bf16x8*)(dst+512) = vl;
  }
}

// ---------- split hidden -> h0/h1 bf16 hi/lo ----------
__global__ __launch_bounds__(256) void k_split_h(const float* __restrict__ hidden,
    __bf16* __restrict__ h0h, __bf16* __restrict__ h0l,
    __bf16* __restrict__ h1h, __bf16* __restrict__ h1l){
  int i = blockIdx.x*256 + threadIdx.x;
  float x = hidden[i];
  if(i < 16384) split2(x, &h0h[i], &h0l[i]);
  else { int j = i - 16384; split2(x, &h1h[j], &h1l[j]); }
}

// ---------- fp32 -> bf16 (x8) ----------
__global__ __launch_bounds__(256) void k_cvt16(const float* __restrict__ in,
                                               __bf16* __restrict__ out){
  int i = blockIdx.x*256 + threadIdx.x;
  const float* p = in + (size_t)i*8;
  f32x4 f0 = ld4(p), f1 = ld4(p+4);
  bf16x8 v;
  #pragma unroll
  for(int e=0;e<4;++e){ v[e] = (__bf16)f0[e]; v[4+e] = (__bf16)f1[e]; }
  *(bf16x8*)(out + (size_t)i*8) = v;
}

// ---------- zero barrier flags ----------
__global__ void k_init(int* flags){ flags[threadIdx.x] = 0; }

// ---------- gload_lds panel staging (normal cached path; read-only weights) ----------
__device__ __forceinline__ void stage_tile(const __bf16* __restrict__ Wp, int jt,
                                           char* stage, int w, int lane){
  const char* gsrc = (const char*)Wp + (size_t)jt*65536 + (size_t)w*8192 + lane*16;
  char* ldst = stage + w*8192;
  #pragma unroll
  for(int i=0;i<8;++i)
    __builtin_amdgcn_global_load_lds(
      (const __attribute__((address_space(1))) unsigned int*)(gsrc + i*1024),
      (__attribute__((address_space(3))) unsigned int*)(ldst + i*1024), 16, 0, 0);
}

// ---------- MFMA GEMV with bypass A-frags + bypass output stores ----------
__device__ __forceinline__ void gemv_byp(const __bf16* hh, const __bf16* hl,
                                         const __bf16* __restrict__ Wp, int jt,
                                         char* stage, float* out, int ldo){
  int tid = threadIdx.x, lane = tid & 63, w = tid >> 6;
  const __bf16* Ah = hh + (lane&15)*1024 + (lane>>4)*8;
  const __bf16* Al = hl + (lane&15)*1024 + (lane>>4)*8;
  bf16x8 ah[4], al[4];
  #pragma unroll
  for(int kk=0;kk<4;++kk){
    ah[kk] = ldx4b_bf(Ah + (w*4+kk)*32);
    al[kk] = ldx4b_bf(Al + (w*4+kk)*32);
  }
  stage_tile(Wp, jt, stage, w, lane);
  WAIT_VM0();
  f32x4 acc = {0.f,0.f,0.f,0.f};
  #pragma unroll
  for(int kk=0;kk<4;++kk){
    bf16x8 bh = *(const bf16x8*)(stage + w*8192 + kk*2048 + lane*16);
    bf16x8 bl = *(const bf16x8*)(stage + w*8192 + kk*2048 + 1024 + lane*16);
    acc = MFMA16(ah[kk], bh, acc, 0,0,0);
    acc = MFMA16(al[kk], bh, acc, 0,0,0);
    acc = MFMA16(ah[kk], bl, acc, 0,0,0);
  }
  *(f32x4*)(stage + w*8192 + lane*16) = acc;
  __syncthreads();
  if(tid < 64){
    f32x4 s = *(const f32x4*)(stage + tid*16);
    #pragma unroll
    for(int k=1;k<8;++k) s += *(const f32x4*)(stage + k*8192 + tid*16);
    int j = jt*16 + (tid & 15);
    #pragma unroll
    for(int i=0;i<4;++i) stfb(out + (size_t)((tid>>4)*4 + i)*ldo + j, s[i]);
  }
  __syncthreads();
}

struct RecP {
  const __bf16 *Whh1p, *Wqp, *Wih1p, *Whh0p;
  const float *kp, *EW, *GX0x, *v_att;
  const float *b_hh0, *b_ih1, *b_hh1;
  const float *hidden;
  __bf16 *h0h, *h0l, *h1h, *h1l;
  float *gh0, *gh1, *parts;
  float *h0A, *h0B, *h1A, *h1B;
  __bf16 *Hb;
  int *flags;
};

// ---------- persistent recurrence: 256 blocks x 512 threads ----------
__global__ __launch_bounds__(512) void k_rec(RecP P){
  __shared__ __align__(16) char smem[65536];
  int blk = blockIdx.x, tid = threadIdx.x;
  int lane = tid & 63, w = tid >> 6;

  // boot: gh0(0) = h0(0) @ Whh0^T  (blocks 64..255)
  if(blk >= 64) gemv_byp(P.h0h, P.h0l, P.Whh0p, blk-64, smem, P.gh0, 3072);
  barrier_dev(P.flags, blk, 1);

  for(int t=0;t<64;++t){
    const float* h0i = (t==0)? P.hidden           : ((t&1)? P.h0A : P.h0B);
    float*       h0o = (t&1)? P.h0B : P.h0A;
    const float* h1i = (t==0)? P.hidden + 16*1024 : ((t&1)? P.h1A : P.h1B);
    float*       h1o = (t&1)? P.h1B : P.h1A;

    // ================= P1: gh1 (192 blk) | q + tanh-score partials (64 blk) ==
    if(blk < 192){
      gemv_byp(P.h1h, P.h1l, P.Whh1p, blk, smem, P.gh1, 3072);
    } else {
      int slice = blk - 192;
      const __bf16* Ah = P.h1h + (lane&15)*1024 + (lane>>4)*8;
      const __bf16* Al = P.h1l + (lane&15)*1024 + (lane>>4)*8;
      bf16x8 ah[4], al[4];
      #pragma unroll
      for(int kk=0;kk<4;++kk){
        ah[kk] = ldx4b_bf(Ah + (w*4+kk)*32);
        al[kk] = ldx4b_bf(Al + (w*4+kk)*32);
      }
      stage_tile(P.Wqp, slice, smem, w, lane);
      WAIT_VM0();
      f32x4 acc = {0.f,0.f,0.f,0.f};
      #pragma unroll
      for(int kk=0;kk<4;++kk){
        bf16x8 bh = *(const bf16x8*)(smem + w*8192 + kk*2048 + lane*16);
        bf16x8 bl = *(const bf16x8*)(smem + w*8192 + kk*2048 + 1024 + lane*16);
        acc = MFMA16(ah[kk], bh, acc, 0,0,0);
        acc = MFMA16(al[kk], bh, acc, 0,0,0);
        acc = MFMA16(ah[kk], bl, acc, 0,0,0);
      }
      *(f32x4*)(smem + w*8192 + lane*16) = acc;
      __syncthreads();
      float* qsp = (float*)(smem + 1024);      // qs[16 b][16 a_local]
      if(tid < 64){
        f32x4 s = *(const f32x4*)(smem + tid*16);
        #pragma unroll
        for(int k=1;k<8;++k) s += *(const f32x4*)(smem + k*8192 + tid*16);
        #pragma unroll
        for(int i=0;i<4;++i) qsp[((tid>>4)*4 + i)*16 + (tid&15)] = s[i];
      }
      __syncthreads();
      const float* vp = P.v_att + slice*16;
      f32x4 v0 = ld4(vp), v1 = ld4(vp+4), v2 = ld4(vp+8), v3 = ld4(vp+12);
      #pragma unroll
      for(int r=0;r<2;++r){
        int pair = r*512 + tid;          // b*64 + s
        int b = pair >> 6;
        const float* kpr = P.kp + (size_t)pair*1024 + slice*16;
        f32x4 c0 = ld4(kpr), c1 = ld4(kpr+4), c2 = ld4(kpr+8), c3 = ld4(kpr+12);
        const float* qb = qsp + b*16;
        float acc2 = 0.f;
        #pragma unroll
        for(int e=0;e<4;++e){
          acc2 += v0[e]*tanhf(qb[e]     + c0[e]);
          acc2 += v1[e]*tanhf(qb[4+e]   + c1[e]);
          acc2 += v2[e]*tanhf(qb[8+e]   + c2[e]);
          acc2 += v3[e]*tanhf(qb[12+e]  + c3[e]);
        }
        stfb(P.parts + (size_t)slice*1024 + pair, acc2);
      }
    }
    barrier_dev(P.flags, blk, 3*t+2);

    // ================= P2: softmax + attn.EW + GRU0 -> h0n (all 256 blk) =====
    {
      float* ssum = (float*)smem;              // [256][2]
      float* scv  = (float*)(smem + 2048);     // [4][64]
      float* sden = (float*)(smem + 3072);     // [4]
      float* prt  = (float*)(smem + 3136);     // [8][4][16][3]
      int jt = blk >> 2, bq = blk & 3;
      {
        int hf = tid >> 8, p = tid & 255;
        int pair = bq*256 + p;
        const float* base = P.parts + (size_t)(hf*32)*1024 + pair;
        float v[32];
        #pragma unroll
        for(int k=0;k<32;++k) v[k] = ldfb(base + (size_t)k*1024);
        WAIT_VM0();
        float s = 0.f;
        #pragma unroll
        for(int k=0;k<32;++k) s += v[k];
        ssum[p*2 + hf] = s;
      }
      __syncthreads();
      if(tid < 256) scv[(tid>>6)*64 + (tid&63)] = expf(ssum[tid*2] + ssum[tid*2+1]);
      __syncthreads();
      if(tid < 4){
        float d = 0.f;
        #pragma unroll
        for(int s2=0;s2<64;++s2) d += scv[tid*64 + s2];
        sden[tid] = d;
      }
      __syncthreads();
      int bl = lane >> 4, jl = lane & 15;
      int b = bq*4 + bl, col = jt*16 + jl;
      float a0=0.f, a1=0.f, a2=0.f;
      const float* ewp = P.EW + ((size_t)(b*64 + w*8))*3072 + col;
      #pragma unroll
      for(int si=0; si<8; ++si){
        float e = scv[bl*64 + w*8 + si];
        const float* r2 = ewp + (size_t)si*3072;
        a0 += e*r2[0]; a1 += e*r2[1024]; a2 += e*r2[2048];
      }
      prt[((w*4 + bl)*16 + jl)*3 + 0] = a0;
      prt[((w*4 + bl)*16 + jl)*3 + 1] = a1;
      prt[((w*4 + bl)*16 + jl)*3 + 2] = a2;
      __syncthreads();
      if(tid < 64){
        int bl2 = tid >> 4, jl2 = tid & 15;
        int b2 = bq*4 + bl2, j = jt*16 + jl2;
        float xr=0.f, xz=0.f, xn=0.f;
        #pragma unroll
        for(int k=0;k<8;++k){
          xr += prt[((k*4 + bl2)*16 + jl2)*3 + 0];
          xz += prt[((k*4 + bl2)*16 + jl2)*3 + 1];
          xn += prt[((k*4 + bl2)*16 + jl2)*3 + 2];
        }
        float g0r = ldfb(P.gh0 + (size_t)b2*3072 + j);
        float g0z = ldfb(P.gh0 + (size_t)b2*3072 + 1024 + j);
        float g0n = ldfb(P.gh0 + (size_t)b2*3072 + 2048 + j);
        float hprev = ldfb(h0i + b2*1024 + j);
        WAIT_VM0();
        float inv = 1.0f / sden[bl2];
        const float* gx = P.GX0x + ((size_t)t*16 + b2)*3072 + j;   // includes b_ih0
        float r = sigm(xr*inv + gx[0]    + g0r + P.b_hh0[j]);
        float z = sigm(xz*inv + gx[1024] + g0z + P.b_hh0[1024+j]);
        float n = tanhf(xn*inv + gx[2048] + r*(g0n + P.b_hh0[2048+j]));
        float hnew = (1.f-z)*n + z*hprev;
        stfb(h0o + b2*1024 + j, hnew);
        __bf16 hh2, ll2; split2(hnew, &hh2, &ll2);
        stsb(P.h0h + b2*1024 + j, hh2);
        stsb(P.h0l + b2*1024 + j, ll2);
      }
    }
    barrier_dev(P.flags, blk, 3*t+3);

    // ================= P3: h1n 3-gate (64 blk) | gh0(t+1) (192 blk) ==========
    if(blk >= 64){
      gemv_byp(P.h0h, P.h0l, P.Whh0p, blk-64, smem, P.gh0, 3072);
    } else {
      const __bf16* Ah = P.h0h + (lane&15)*1024 + (lane>>4)*8;
      const __bf16* Al = P.h0l + (lane&15)*1024 + (lane>>4)*8;
      bf16x8 ah[4], al[4];
      #pragma unroll
      for(int kk=0;kk<4;++kk){
        ah[kk] = ldx4b_bf(Ah + (w*4+kk)*32);
        al[kk] = ldx4b_bf(Al + (w*4+kk)*32);
      }
      f32x4 accg[3];
      bf16x8 bh[4], bl[4];
      stage_tile(P.Wih1p, 0*64 + blk, smem, w, lane);
      WAIT_VM0();
      #pragma unroll
      for(int g=0; g<3; ++g){
        if(g) WAIT_VM0();
        #pragma unroll
        for(int kk=0;kk<4;++kk){
          bh[kk] = *(const bf16x8*)(smem + w*8192 + kk*2048 + lane*16);
          bl[kk] = *(const bf16x8*)(smem + w*8192 + kk*2048 + 1024 + lane*16);
        }
        if(g < 2){
          WAIT_LGKM0();
          stage_tile(P.Wih1p, (g+1)*64 + blk, smem, w, lane);
        }
        f32x4 acc = {0.f,0.f,0.f,0.f};
        #pragma unroll
        for(int kk=0;kk<4;++kk){
          acc = MFMA16(ah[kk], bh[kk], acc, 0,0,0);
          acc = MFMA16(al[kk], bh[kk], acc, 0,0,0);
          acc = MFMA16(ah[kk], bl[kk], acc, 0,0,0);
        }
        accg[g] = acc;
      }
      #pragma unroll
      for(int g=0; g<3; ++g)
        *(f32x4*)(smem + w*8192 + g*1024 + lane*16) = accg[g];
      __syncthreads();
      float* xgp = (float*)(smem + 4096);     // xg[3][16][16]
      if(tid < 192){
        int g = tid >> 6, tt = tid & 63;
        f32x4 s = *(const f32x4*)(smem + g*1024 + tt*16);
        #pragma unroll
        for(int k=1;k<8;++k) s += *(const f32x4*)(smem + k*8192 + g*1024 + tt*16);
        #pragma unroll
        for(int i=0;i<4;++i) xgp[g*256 + ((tt>>4)*4 + i)*16 + (tt&15)] = s[i];
      }
      __syncthreads();
      if(tid < 256){
        int b = tid >> 4, jl = tid & 15, j = blk*16 + jl;
        float g1r = ldfb(P.gh1 + (size_t)b*3072 + j);
        float g1z = ldfb(P.gh1 + (size_t)b*3072 + 1024 + j);
        float g1n = ldfb(P.gh1 + (size_t)b*3072 + 2048 + j);
        float hprev = ldfb(h1i + b*1024 + j);
        WAIT_VM0();
        float xr = xgp[0*256 + b*16 + jl] + P.b_ih1[j];
        float xz = xgp[1*256 + b*16 + jl] + P.b_ih1[1024+j];
        float xn = xgp[2*256 + b*16 + jl] + P.b_ih1[2048+j];
        float r = sigm(xr + g1r + P.b_hh1[j]);
        float z = sigm(xz + g1z + P.b_hh1[1024+j]);
        float n = tanhf(xn + r*(g1n + P.b_hh1[2048+j]));
        float hnew = (1.f-z)*n + z*hprev;
        stfb(h1o + b*1024 + j, hnew);
        __bf16 hh2, ll2; split2(hnew, &hh2, &ll2);
        stsb(P.h1h + b*1024 + j, hh2);
        stsb(P.h1l + b*1024 + j, ll2);
        P.Hb[((size_t)t*16 + b)*1024 + j] = (__bf16)hnew;   // normal store (post-kernel consumer)
      }
    }
    barrier_dev(P.flags, blk, 3*t+4);
  }
}

// ---------- logits: BM=256, BN=128, 512 thr, bf16 B, LDS-staged (round-5) ----------
__global__ __launch_bounds__(512) void k_logits(
    const __bf16* __restrict__ Hb, const __bf16* __restrict__ Wb,
    const float* __restrict__ b_out, float* __restrict__ out)
{
  int c = blockIdx.x & 7, j = blockIdx.x >> 3;
  int x = j & 3, y = (j >> 2)*8 + c;
  if(y >= 250) return;
  int tm0 = x*256, tn0 = y*128;
  __shared__ __align__(16) __bf16 As[256][40];
  __shared__ __align__(16) __bf16 Bs[128][40];
  int tid = threadIdx.x;
  int lane = tid & 63, wave = tid >> 6;
  int wr = wave >> 1, wc = wave & 1;
  int qq = lane >> 4, rr = lane & 15;
  f32x4 acc[4][4] = {};
  int ar = tid >> 2, ak = (tid & 3) * 8;
  for(int k0=0;k0<1024;k0+=32){
    bf16x8 a0v = *(const bf16x8*)(Hb + (size_t)(tm0+ar)*1024     + k0 + ak);
    bf16x8 a1v = *(const bf16x8*)(Hb + (size_t)(tm0+ar+128)*1024 + k0 + ak);
    bf16x8 bv  = *(const bf16x8*)(Wb + (size_t)(tn0+ar)*1024     + k0 + ak);
    __syncthreads();
    *(bf16x8*)&As[ar][ak]     = a0v;
    *(bf16x8*)&As[ar+128][ak] = a1v;
    *(bf16x8*)&Bs[ar][ak]     = bv;
    __syncthreads();
    bf16x8 af[4], bfr[4];
    #pragma unroll
    for(int mi=0;mi<4;++mi) af[mi]  = *(const bf16x8*)&As[wr*64 + mi*16 + rr][qq*8];
    #pragma unroll
    for(int ni=0;ni<4;++ni) bfr[ni] = *(const bf16x8*)&Bs[wc*64 + ni*16 + rr][qq*8];
    #pragma unroll
    for(int mi=0;mi<4;++mi)
      #pragma unroll
      for(int ni=0;ni<4;++ni)
        acc[mi][ni] = MFMA16(af[mi], bfr[ni], acc[mi][ni], 0,0,0);
  }
  #pragma unroll
  for(int mi=0;mi<4;++mi)
    #pragma unroll
    for(int ni=0;ni<4;++ni)
      #pragma unroll
      for(int i=0;i<4;++i){
        int m = tm0 + wr*64 + mi*16 + qq*4 + i;
        int v = tn0 + wc*64 + ni*16 + rr;
        int bb = m & 15, tt = m >> 4;
        out[((size_t)bb*64 + tt)*32000 + v] = acc[mi][ni][i] + b_out[v];
      }
}

extern "C" void kernel_launch(void* const* d_in, const int* in_sizes, int n_in,
                              void* d_out, int out_size, void* d_ws, size_t ws_size,
                              hipStream_t stream){
  const int*   tgt    = (const int*)d_in[0];
  const float* hidden = (const float*)d_in[1];
  const float* enc    = (const float*)d_in[2];
  const float* emb    = (const float*)d_in[3];
  const float* Wq     = (const float*)d_in[4];
  const float* Wk     = (const float*)d_in[5];
  const float* v_att  = (const float*)d_in[6];
  const float* W_ih0  = (const float*)d_in[7];
  const float* W_hh0  = (const float*)d_in[8];
  const float* b_ih0  = (const float*)d_in[9];
  const float* b_hh0  = (const float*)d_in[10];
  const float* W_ih1  = (const float*)d_in[11];
  const float* W_hh1  = (const float*)d_in[12];
  const float* b_ih1  = (const float*)d_in[13];
  const float* b_hh1  = (const float*)d_in[14];
  const float* W_out  = (const float*)d_in[15];
  const float* b_out  = (const float*)d_in[16];
  float* out = (float*)d_out;

  float* ws = (float*)d_ws;
  size_t off = 0;
  auto alloc = [&](size_t n){ float* p = ws + off; off += n; return p; };
  float*  kp     = alloc((size_t)1024*1024);
  float*  GX0x   = alloc((size_t)1024*3072);
  float*  EW     = alloc((size_t)1024*3072);
  __bf16* Whh0p  = (__bf16*)alloc((size_t)3072*1024);
  __bf16* Whh1p  = (__bf16*)alloc((size_t)3072*1024);
  __bf16* Wih1p  = (__bf16*)alloc((size_t)3072*1024);
  __bf16* Wqp    = (__bf16*)alloc((size_t)1024*1024);
  float*  gh0    = alloc((size_t)16*3072);
  float*  gh1    = alloc((size_t)16*3072);
  float*  parts  = alloc((size_t)64*1024);
  float*  h0A    = alloc((size_t)16*1024);
  float*  h0B    = alloc((size_t)16*1024);
  float*  h1A    = alloc((size_t)16*1024);
  float*  h1B    = alloc((size_t)16*1024);
  __bf16* h0sh   = (__bf16*)alloc((size_t)8192);
  __bf16* h0sl   = (__bf16*)alloc((size_t)8192);
  __bf16* h1sh   = (__bf16*)alloc((size_t)8192);
  __bf16* h1sl   = (__bf16*)alloc((size_t)8192);
  float*  Hb_f   = alloc((size_t)512*1024);
  int*    flags  = (int*)alloc((size_t)256);
  __bf16* Hb     = (__bf16*)Hb_f;
  // aliases: emb_tok lives where Hb will go; WT where EW will go; Woutb
  // overlays kp..Wqp (dead after the recurrence; Hb/flags sit above 16.4M floats).
  float*  emb_tok = Hb_f;
  float*  WT      = EW;
  __bf16* Woutb   = (__bf16*)ws;          // 32000x1024 bf16 = 16.384M floats
  (void)ws_size; (void)in_sizes; (void)n_in; (void)out_size;

  // ---- setup ----
  k_gather<<<1024,256,0,stream>>>(tgt, emb, emb_tok);
  k_transpose<<<dim3(32,32),256,0,stream>>>(Wk, WT, 1024, 1024);
  k_gemm_s<<<dim3(8,16),256,0,stream>>>(enc,1024, WT,1024, nullptr, kp, 1024, 1024);
  k_gemm_s<<<dim3(8,48),256,0,stream>>>(emb_tok,512, W_ih0,1536, b_ih0, GX0x, 3072, 512);
  k_gemm_s<<<dim3(8,48),256,0,stream>>>(enc,1024, W_ih0+512,1536, nullptr, EW, 3072, 1024);
  k_pack_wT<<<64,256,0,stream>>>(Wq, 1024, Wqp);
  k_pack_w<<<192,256,0,stream>>>(W_hh0, Whh0p);
  k_pack_w<<<192,256,0,stream>>>(W_hh1, Whh1p);
  k_pack_w<<<192,256,0,stream>>>(W_ih1, Wih1p);
  k_split_h<<<128,256,0,stream>>>(hidden, h0sh, h0sl, h1sh, h1sl);
  k_init<<<1,256,0,stream>>>(flags);

  // ---- persistent recurrence (custom L2-preserving barriers, no grid.sync) ----
  RecP P;
  P.Whh1p = Whh1p; P.Wqp = Wqp; P.Wih1p = Wih1p; P.Whh0p = Whh0p;
  P.kp = kp; P.EW = EW; P.GX0x = GX0x; P.v_att = v_att;
  P.b_hh0 = b_hh0; P.b_ih1 = b_ih1; P.b_hh1 = b_hh1;
  P.hidden = hidden;
  P.h0h = h0sh; P.h0l = h0sl; P.h1h = h1sh; P.h1l = h1sl;
  P.gh0 = gh0; P.gh1 = gh1; P.parts = parts;
  P.h0A = h0A; P.h0B = h0B; P.h1A = h1A; P.h1B = h1B;
  P.Hb = Hb; P.flags = flags;
  void* args[] = { &P };
  hipLaunchCooperativeKernel((const void*)k_rec, dim3(256), dim3(512), args, 0, stream);

  // ---- deferred logits ----
  k_cvt16<<<16000,256,0,stream>>>(W_out, Woutb);
  k_logits<<<1024,512,0,stream>>>(Hb, Woutb, b_out, out);
}

// Round 8
// 3736.497 us; speedup vs baseline: 1.0006x; 1.0006x over previous
//
#include <hip/hip_runtime.h>
#include <hip/hip_cooperative_groups.h>
#include <hip/hip_bf16.h>
#include <math.h>

// V=32000 E=512 H=1024 A=1024 L=2 B=16 T=64 S=64
typedef __bf16 bf16x8 __attribute__((ext_vector_type(8)));
typedef float  f32x4  __attribute__((ext_vector_type(4)));
typedef int    i32x4  __attribute__((ext_vector_type(4)));

#define MFMA16 __builtin_amdgcn_mfma_f32_16x16x32_bf16
#define WAIT_VM0()   { asm volatile("s_waitcnt vmcnt(0)" ::: "memory");   __builtin_amdgcn_sched_barrier(0); }
#define WAIT_LGKM0() { asm volatile("s_waitcnt lgkmcnt(0)" ::: "memory"); __builtin_amdgcn_sched_barrier(0); }

__device__ __forceinline__ float sigm(float x){ return 1.0f/(1.0f+expf(-x)); }
__device__ __forceinline__ f32x4 ld4(const float* p){ return *(const f32x4*)p; }
__device__ __forceinline__ void split2(float x, __bf16* h, __bf16* l){
  __bf16 hh = (__bf16)x; *h = hh; *l = (__bf16)(x - (float)hh);
}

// ======== L2-bypass (device-coherent) access helpers: sc0 sc1 ========
__device__ __forceinline__ bf16x8 ldx4b_bf(const __bf16* p){
  bf16x8 r;
  asm volatile("global_load_dwordx4 %0, %1, off sc0 sc1" : "=v"(r) : "v"(p) : "memory");
  return r;
}
__device__ __forceinline__ float ldfb(const float* p){
  float r;
  asm volatile("global_load_dword %0, %1, off sc0 sc1" : "=v"(r) : "v"(p) : "memory");
  return r;
}
__device__ __forceinline__ void stfb(float* p, float v){
  asm volatile("global_store_dword %0, %1, off sc0 sc1" :: "v"(p), "v"(v) : "memory");
}
__device__ __forceinline__ void stib(int* p, int v){
  asm volatile("global_store_dword %0, %1, off sc0 sc1" :: "v"(p), "v"(v) : "memory");
}
__device__ __forceinline__ void stsb(__bf16* p, __bf16 v){
  unsigned int b = (unsigned int)__builtin_bit_cast(unsigned short, v);
  asm volatile("global_store_short %0, %1, off sc0 sc1" :: "v"(p), "v"(b) : "memory");
}

// ======== decentralized L2-preserving grid barrier ========
// Each block publishes flags[blk]=target (bypass store); wave 0 polls all 256
// flags (one dwordx4/lane) until min >= target. No atomics, no cache nukes.
__device__ __forceinline__ void barrier_dev(int* flags, int blk, int target){
  WAIT_VM0();
  __syncthreads();                 // all waves' bypass stores drained
  int tid = threadIdx.x;
  if(tid == 0) stib(flags + blk, target);
  if(tid < 64){
    const int* p = flags + tid*4;
    for(;;){
      i32x4 v;
      asm volatile("global_load_dwordx4 %0, %1, off sc0 sc1\n\ts_waitcnt vmcnt(0)"
                   : "=v"(v) : "v"(p) : "memory");
      int m01 = v[0] < v[1] ? v[0] : v[1];
      int m23 = v[2] < v[3] ? v[2] : v[3];
      int m = m01 < m23 ? m01 : m23;
      if(__all(m >= target)) break;
      __builtin_amdgcn_s_sleep(4);
    }
  }
  __syncthreads();
}

// ---------- transpose fp32 ----------
__global__ __launch_bounds__(256) void k_transpose(const float* __restrict__ in,
                                                   float* __restrict__ out, int R, int C){
  __shared__ float tile[32][33];
  int c0 = blockIdx.x*32, r0 = blockIdx.y*32;
  int tx = threadIdx.x & 31, ty = threadIdx.x >> 5;
  for(int i=ty;i<32;i+=8) tile[i][tx] = in[(size_t)(r0+i)*C + c0+tx];
  __syncthreads();
  for(int i=ty;i<32;i+=8) out[(size_t)(c0+i)*R + r0+tx] = tile[tx][i];
}

// ---------- gather fp32 ----------
__global__ __launch_bounds__(256) void k_gather(const int* __restrict__ tgt,
                                                const float* __restrict__ emb,
                                                float* __restrict__ emb_tok){
  int m = blockIdx.x;            // m = t*16+b
  int t = m >> 4, b = m & 15;
  int row = tgt[b*64 + t];
  const float* src = emb + (size_t)row*512;
  float* dst = emb_tok + (size_t)m*512;
  for(int e=threadIdx.x;e<512;e+=256) dst[e] = src[e];
}

// ---------- setup GEMM (hi/lo MFMA, fp32-accurate) ----------
__global__ __launch_bounds__(256) void k_gemm_s(
    const float* __restrict__ A, int lda,
    const float* __restrict__ Bt, int ldb,
    const float* __restrict__ bias,
    float* __restrict__ C, int N, int K)
{
  __shared__ __align__(16) __bf16 Ash[128][40];
  __shared__ __align__(16) __bf16 Asl[128][40];
  __shared__ __align__(16) __bf16 Bsh[64][40];
  __shared__ __align__(16) __bf16 Bsl[64][40];
  int tid = threadIdx.x;
  int m0 = blockIdx.x*128, n0 = blockIdx.y*64;
  int lane = tid & 63, wave = tid >> 6;
  int wr = wave >> 1, wc = wave & 1;
  int qq = lane >> 4, rr = lane & 15;
  f32x4 acc[4][2] = {};
  int ar = tid >> 1, ak = (tid & 1)*16;
  int br = tid >> 2, bk = (tid & 3)*8;
  for(int k0=0;k0<K;k0+=32){
    const float* ap = A + (size_t)(m0+ar)*lda + k0 + ak;
    f32x4 a0 = ld4(ap), a1 = ld4(ap+4), a2 = ld4(ap+8), a3 = ld4(ap+12);
    const float* bp = Bt + (size_t)(n0+br)*ldb + k0 + bk;
    f32x4 b0 = ld4(bp), b1 = ld4(bp+4);
    __syncthreads();
    #pragma unroll
    for(int e=0;e<4;++e){
      split2(a0[e], &Ash[ar][ak+e],    &Asl[ar][ak+e]);
      split2(a1[e], &Ash[ar][ak+4+e],  &Asl[ar][ak+4+e]);
      split2(a2[e], &Ash[ar][ak+8+e],  &Asl[ar][ak+8+e]);
      split2(a3[e], &Ash[ar][ak+12+e], &Asl[ar][ak+12+e]);
      split2(b0[e], &Bsh[br][bk+e],    &Bsl[br][bk+e]);
      split2(b1[e], &Bsh[br][bk+4+e],  &Bsl[br][bk+4+e]);
    }
    __syncthreads();
    bf16x8 afh[4], afl[4], bfh[2], bfl[2];
    #pragma unroll
    for(int mi=0;mi<4;++mi){
      afh[mi] = *(const bf16x8*)&Ash[wr*64 + mi*16 + rr][qq*8];
      afl[mi] = *(const bf16x8*)&Asl[wr*64 + mi*16 + rr][qq*8];
    }
    #pragma unroll
    for(int ni=0;ni<2;++ni){
      bfh[ni] = *(const bf16x8*)&Bsh[wc*32 + ni*16 + rr][qq*8];
      bfl[ni] = *(const bf16x8*)&Bsl[wc*32 + ni*16 + rr][qq*8];
    }
    #pragma unroll
    for(int mi=0;mi<4;++mi)
      #pragma unroll
      for(int ni=0;ni<2;++ni){
        acc[mi][ni] = MFMA16(afh[mi], bfh[ni], acc[mi][ni], 0,0,0);
        acc[mi][ni] = MFMA16(afl[mi], bfh[ni], acc[mi][ni], 0,0,0);
        acc[mi][ni] = MFMA16(afh[mi], bfl[ni], acc[mi][ni], 0,0,0);
      }
  }
  #pragma unroll
  for(int mi=0;mi<4;++mi)
    #pragma unroll
    for(int ni=0;ni<2;++ni)
      #pragma unroll
      for(int i=0;i<4;++i){
        int m = m0 + wr*64 + mi*16 + qq*4 + i;
        int n = n0 + wc*32 + ni*16 + rr;
        C[(size_t)m*N + n] = acc[mi][ni][i] + (bias? bias[n] : 0.f);
      }
}

// ---------- pack W[J][1024] fp32 -> MFMA B-frag panels, bf16 hi/lo ----------
__global__ __launch_bounds__(256) void k_pack_w(const float* __restrict__ W,
                                                __bf16* __restrict__ Wp){
  int jt = blockIdx.x, tid = threadIdx.x;
  #pragma unroll
  for(int it=0; it<8; ++it){
    int pos = it*256 + tid;
    int kt = pos>>6, l = pos&63;
    const float* src = W + (size_t)(jt*16 + (l&15))*1024 + kt*32 + (l>>4)*8;
    f32x4 s0 = ld4(src), s1 = ld4(src+4);
    bf16x8 vh, vl;
    #pragma unroll
    for(int e=0;e<4;++e){
      __bf16 h, lo;
      split2(s0[e], &h, &lo); vh[e]   = h; vl[e]   = lo;
      split2(s1[e], &h, &lo); vh[4+e] = h; vl[4+e] = lo;
    }
    __bf16* dst = Wp + ((size_t)(jt*32 + kt))*1024 + l*8;
    *(bf16x8*)dst       = vh;
    *(bf16x8*)(dst+512) = vl;
  }
}

// ---------- pack, reading W transposed ----------
__global__ __launch_bounds__(256) void k_pack_wT(const float* __restrict__ W, int ldw,
                                                 __bf16* __restrict__ Wp){
  int jt = blockIdx.x, tid = threadIdx.x;
  #pragma unroll
  for(int it=0; it<8; ++it){
    int pos = it*256 + tid;
    int kt = pos>>6, l = pos&63;
    int j = jt*16 + (l&15);
    int kbase = kt*32 + (l>>4)*8;
    bf16x8 vh, vl;
    #pragma unroll
    for(int e=0;e<8;++e){
      float x = W[(size_t)(kbase+e)*ldw + j];
      __bf16 h = (__bf16)x;
      vh[e] = h; vl[e] = (__bf16)(x - (float)h);
    }
    __bf16* dst = Wp + ((size_t)(jt*32 + kt))*1024 + l*8;
    *(bf16x8*)dst       = vh;
    *(bf16x8*)(dst+512) = vl;
  }
}

// ---------- split hidden -> h0/h1 bf16 hi/lo ----------
__global__ __launch_bounds__(256) void k_split_h(const float* __restrict__ hidden,
    __bf16* __restrict__ h0h, __bf16* __restrict__ h0l,
    __bf16* __restrict__ h1h, __bf16* __restrict__ h1l){
  int i = blockIdx.x*256 + threadIdx.x;
  float x = hidden[i];
  if(i < 16384) split2(x, &h0h[i], &h0l[i]);
  else { int j = i - 16384; split2(x, &h1h[j], &h1l[j]); }
}

// ---------- fp32 -> bf16 (x8) ----------
__global__ __launch_bounds__(256) void k_cvt16(const float* __restrict__ in,
                                               __bf16* __restrict__ out){
  int i = blockIdx.x*256 + threadIdx.x;
  const float* p = in + (size_t)i*8;
  f32x4 f0 = ld4(p), f1 = ld4(p+4);
  bf16x8 v;
  #pragma unroll
  for(int e=0;e<4;++e){ v[e] = (__bf16)f0[e]; v[4+e] = (__bf16)f1[e]; }
  *(bf16x8*)(out + (size_t)i*8) = v;
}

// ---------- zero barrier flags ----------
__global__ void k_init(int* flags){ flags[threadIdx.x] = 0; }

// ---------- gload_lds panel staging (normal cached path; read-only weights) ----------
__device__ __forceinline__ void stage_tile(const __bf16* __restrict__ Wp, int jt,
                                           char* stage, int w, int lane){
  const char* gsrc = (const char*)Wp + (size_t)jt*65536 + (size_t)w*8192 + lane*16;
  char* ldst = stage + w*8192;
  #pragma unroll
  for(int i=0;i<8;++i)
    __builtin_amdgcn_global_load_lds(
      (const __attribute__((address_space(1))) unsigned int*)(gsrc + i*1024),
      (__attribute__((address_space(3))) unsigned int*)(ldst + i*1024), 16, 0, 0);
}

// ---------- MFMA GEMV with bypass A-frags + bypass output stores ----------
__device__ __forceinline__ void gemv_byp(const __bf16* hh, const __bf16* hl,
                                         const __bf16* __restrict__ Wp, int jt,
                                         char* stage, float* out, int ldo){
  int tid = threadIdx.x, lane = tid & 63, w = tid >> 6;
  const __bf16* Ah = hh + (lane&15)*1024 + (lane>>4)*8;
  const __bf16* Al = hl + (lane&15)*1024 + (lane>>4)*8;
  bf16x8 ah[4], al[4];
  #pragma unroll
  for(int kk=0;kk<4;++kk){
    ah[kk] = ldx4b_bf(Ah + (w*4+kk)*32);
    al[kk] = ldx4b_bf(Al + (w*4+kk)*32);
  }
  stage_tile(Wp, jt, stage, w, lane);
  WAIT_VM0();
  f32x4 acc = {0.f,0.f,0.f,0.f};
  #pragma unroll
  for(int kk=0;kk<4;++kk){
    bf16x8 bh = *(const bf16x8*)(stage + w*8192 + kk*2048 + lane*16);
    bf16x8 bl = *(const bf16x8*)(stage + w*8192 + kk*2048 + 1024 + lane*16);
    acc = MFMA16(ah[kk], bh, acc, 0,0,0);
    acc = MFMA16(al[kk], bh, acc, 0,0,0);
    acc = MFMA16(ah[kk], bl, acc, 0,0,0);
  }
  *(f32x4*)(stage + w*8192 + lane*16) = acc;
  __syncthreads();
  if(tid < 64){
    f32x4 s = *(const f32x4*)(stage + tid*16);
    #pragma unroll
    for(int k=1;k<8;++k) s += *(const f32x4*)(stage + k*8192 + tid*16);
    int j = jt*16 + (tid & 15);
    #pragma unroll
    for(int i=0;i<4;++i) stfb(out + (size_t)((tid>>4)*4 + i)*ldo + j, s[i]);
  }
  __syncthreads();
}

struct RecP {
  const __bf16 *Whh1p, *Wqp, *Wih1p, *Whh0p;
  const float *kp, *EW, *GX0x, *v_att;
  const float *b_hh0, *b_ih1, *b_hh1;
  const float *hidden;
  __bf16 *h0h, *h0l, *h1h, *h1l;
  float *gh0, *gh1, *parts;
  float *h0A, *h0B, *h1A, *h1B;
  __bf16 *Hb;
  int *flags;
};

// ---------- persistent recurrence: 256 blocks x 512 threads ----------
__global__ __launch_bounds__(512) void k_rec(RecP P){
  __shared__ __align__(16) char smem[65536];
  int blk = blockIdx.x, tid = threadIdx.x;
  int lane = tid & 63, w = tid >> 6;

  // boot: gh0(0) = h0(0) @ Whh0^T  (blocks 64..255)
  if(blk >= 64) gemv_byp(P.h0h, P.h0l, P.Whh0p, blk-64, smem, P.gh0, 3072);
  barrier_dev(P.flags, blk, 1);

  for(int t=0;t<64;++t){
    const float* h0i = (t==0)? P.hidden           : ((t&1)? P.h0A : P.h0B);
    float*       h0o = (t&1)? P.h0B : P.h0A;
    const float* h1i = (t==0)? P.hidden + 16*1024 : ((t&1)? P.h1A : P.h1B);
    float*       h1o = (t&1)? P.h1B : P.h1A;

    // ================= P1: gh1 (192 blk) | q + tanh-score partials (64 blk) ==
    if(blk < 192){
      gemv_byp(P.h1h, P.h1l, P.Whh1p, blk, smem, P.gh1, 3072);
    } else {
      int slice = blk - 192;
      const __bf16* Ah = P.h1h + (lane&15)*1024 + (lane>>4)*8;
      const __bf16* Al = P.h1l + (lane&15)*1024 + (lane>>4)*8;
      bf16x8 ah[4], al[4];
      #pragma unroll
      for(int kk=0;kk<4;++kk){
        ah[kk] = ldx4b_bf(Ah + (w*4+kk)*32);
        al[kk] = ldx4b_bf(Al + (w*4+kk)*32);
      }
      stage_tile(P.Wqp, slice, smem, w, lane);
      WAIT_VM0();
      f32x4 acc = {0.f,0.f,0.f,0.f};
      #pragma unroll
      for(int kk=0;kk<4;++kk){
        bf16x8 bh = *(const bf16x8*)(smem + w*8192 + kk*2048 + lane*16);
        bf16x8 bl = *(const bf16x8*)(smem + w*8192 + kk*2048 + 1024 + lane*16);
        acc = MFMA16(ah[kk], bh, acc, 0,0,0);
        acc = MFMA16(al[kk], bh, acc, 0,0,0);
        acc = MFMA16(ah[kk], bl, acc, 0,0,0);
      }
      *(f32x4*)(smem + w*8192 + lane*16) = acc;
      __syncthreads();
      float* qsp = (float*)(smem + 1024);      // qs[16 b][16 a_local]
      if(tid < 64){
        f32x4 s = *(const f32x4*)(smem + tid*16);
        #pragma unroll
        for(int k=1;k<8;++k) s += *(const f32x4*)(smem + k*8192 + tid*16);
        #pragma unroll
        for(int i=0;i<4;++i) qsp[((tid>>4)*4 + i)*16 + (tid&15)] = s[i];
      }
      __syncthreads();
      const float* vp = P.v_att + slice*16;
      f32x4 v0 = ld4(vp), v1 = ld4(vp+4), v2 = ld4(vp+8), v3 = ld4(vp+12);
      #pragma unroll
      for(int r=0;r<2;++r){
        int pair = r*512 + tid;          // b*64 + s
        int b = pair >> 6;
        const float* kpr = P.kp + (size_t)pair*1024 + slice*16;
        f32x4 c0 = ld4(kpr), c1 = ld4(kpr+4), c2 = ld4(kpr+8), c3 = ld4(kpr+12);
        const float* qb = qsp + b*16;
        float acc2 = 0.f;
        #pragma unroll
        for(int e=0;e<4;++e){
          acc2 += v0[e]*tanhf(qb[e]     + c0[e]);
          acc2 += v1[e]*tanhf(qb[4+e]   + c1[e]);
          acc2 += v2[e]*tanhf(qb[8+e]   + c2[e]);
          acc2 += v3[e]*tanhf(qb[12+e]  + c3[e]);
        }
        stfb(P.parts + (size_t)slice*1024 + pair, acc2);
      }
    }
    barrier_dev(P.flags, blk, 3*t+2);

    // ================= P2: softmax + attn.EW + GRU0 -> h0n (all 256 blk) =====
    {
      float* ssum = (float*)smem;              // [256][2]
      float* scv  = (float*)(smem + 2048);     // [4][64]
      float* sden = (float*)(smem + 3072);     // [4]
      float* prt  = (float*)(smem + 3136);     // [8][4][16][3]
      int jt = blk >> 2, bq = blk & 3;
      {
        int hf = tid >> 8, p = tid & 255;
        int pair = bq*256 + p;
        const float* base = P.parts + (size_t)(hf*32)*1024 + pair;
        float v[32];
        #pragma unroll
        for(int k=0;k<32;++k) v[k] = ldfb(base + (size_t)k*1024);
        WAIT_VM0();
        float s = 0.f;
        #pragma unroll
        for(int k=0;k<32;++k) s += v[k];
        ssum[p*2 + hf] = s;
      }
      __syncthreads();
      if(tid < 256) scv[(tid>>6)*64 + (tid&63)] = expf(ssum[tid*2] + ssum[tid*2+1]);
      __syncthreads();
      if(tid < 4){
        float d = 0.f;
        #pragma unroll
        for(int s2=0;s2<64;++s2) d += scv[tid*64 + s2];
        sden[tid] = d;
      }
      __syncthreads();
      int bl = lane >> 4, jl = lane & 15;
      int b = bq*4 + bl, col = jt*16 + jl;
      float a0=0.f, a1=0.f, a2=0.f;
      const float* ewp = P.EW + ((size_t)(b*64 + w*8))*3072 + col;
      #pragma unroll
      for(int si=0; si<8; ++si){
        float e = scv[bl*64 + w*8 + si];
        const float* r2 = ewp + (size_t)si*3072;
        a0 += e*r2[0]; a1 += e*r2[1024]; a2 += e*r2[2048];
      }
      prt[((w*4 + bl)*16 + jl)*3 + 0] = a0;
      prt[((w*4 + bl)*16 + jl)*3 + 1] = a1;
      prt[((w*4 + bl)*16 + jl)*3 + 2] = a2;
      __syncthreads();
      if(tid < 64){
        int bl2 = tid >> 4, jl2 = tid & 15;
        int b2 = bq*4 + bl2, j = jt*16 + jl2;
        float xr=0.f, xz=0.f, xn=0.f;
        #pragma unroll
        for(int k=0;k<8;++k){
          xr += prt[((k*4 + bl2)*16 + jl2)*3 + 0];
          xz += prt[((k*4 + bl2)*16 + jl2)*3 + 1];
          xn += prt[((k*4 + bl2)*16 + jl2)*3 + 2];
        }
        float g0r = ldfb(P.gh0 + (size_t)b2*3072 + j);
        float g0z = ldfb(P.gh0 + (size_t)b2*3072 + 1024 + j);
        float g0n = ldfb(P.gh0 + (size_t)b2*3072 + 2048 + j);
        float hprev = ldfb(h0i + b2*1024 + j);
        WAIT_VM0();
        float inv = 1.0f / sden[bl2];
        const float* gx = P.GX0x + ((size_t)t*16 + b2)*3072 + j;   // includes b_ih0
        float r = sigm(xr*inv + gx[0]    + g0r + P.b_hh0[j]);
        float z = sigm(xz*inv + gx[1024] + g0z + P.b_hh0[1024+j]);
        float n = tanhf(xn*inv + gx[2048] + r*(g0n + P.b_hh0[2048+j]));
        float hnew = (1.f-z)*n + z*hprev;
        stfb(h0o + b2*1024 + j, hnew);
        __bf16 hh2, ll2; split2(hnew, &hh2, &ll2);
        stsb(P.h0h + b2*1024 + j, hh2);
        stsb(P.h0l + b2*1024 + j, ll2);
      }
    }
    barrier_dev(P.flags, blk, 3*t+3);

    // ================= P3: h1n 3-gate (64 blk) | gh0(t+1) (192 blk) ==========
    if(blk >= 64){
      gemv_byp(P.h0h, P.h0l, P.Whh0p, blk-64, smem, P.gh0, 3072);
    } else {
      const __bf16* Ah = P.h0h + (lane&15)*1024 + (lane>>4)*8;
      const __bf16* Al = P.h0l + (lane&15)*1024 + (lane>>4)*8;
      bf16x8 ah[4], al[4];
      #pragma unroll
      for(int kk=0;kk<4;++kk){
        ah[kk] = ldx4b_bf(Ah + (w*4+kk)*32);
        al[kk] = ldx4b_bf(Al + (w*4+kk)*32);
      }
      f32x4 accg[3];
      bf16x8 bh[4], bl[4];
      stage_tile(P.Wih1p, 0*64 + blk, smem, w, lane);
      WAIT_VM0();
      #pragma unroll
      for(int g=0; g<3; ++g){
        if(g) WAIT_VM0();
        #pragma unroll
        for(int kk=0;kk<4;++kk){
          bh[kk] = *(const bf16x8*)(smem + w*8192 + kk*2048 + lane*16);
          bl[kk] = *(const bf16x8*)(smem + w*8192 + kk*2048 + 1024 + lane*16);
        }
        if(g < 2){
          WAIT_LGKM0();
          stage_tile(P.Wih1p, (g+1)*64 + blk, smem, w, lane);
        }
        f32x4 acc = {0.f,0.f,0.f,0.f};
        #pragma unroll
        for(int kk=0;kk<4;++kk){
          acc = MFMA16(ah[kk], bh[kk], acc, 0,0,0);
          acc = MFMA16(al[kk], bh[kk], acc, 0,0,0);
          acc = MFMA16(ah[kk], bl[kk], acc, 0,0,0);
        }
        accg[g] = acc;
      }
      #pragma unroll
      for(int g=0; g<3; ++g)
        *(f32x4*)(smem + w*8192 + g*1024 + lane*16) = accg[g];
      __syncthreads();
      float* xgp = (float*)(smem + 4096);     // xg[3][16][16]
      if(tid < 192){
        int g = tid >> 6, tt = tid & 63;
        f32x4 s = *(const f32x4*)(smem + g*1024 + tt*16);
        #pragma unroll
        for(int k=1;k<8;++k) s += *(const f32x4*)(smem + k*8192 + g*1024 + tt*16);
        #pragma unroll
        for(int i=0;i<4;++i) xgp[g*256 + ((tt>>4)*4 + i)*16 + (tt&15)] = s[i];
      }
      __syncthreads();
      if(tid < 256){
        int b = tid >> 4, jl = tid & 15, j = blk*16 + jl;
        float g1r = ldfb(P.gh1 + (size_t)b*3072 + j);
        float g1z = ldfb(P.gh1 + (size_t)b*3072 + 1024 + j);
        float g1n = ldfb(P.gh1 + (size_t)b*3072 + 2048 + j);
        float hprev = ldfb(h1i + b*1024 + j);
        WAIT_VM0();
        float xr = xgp[0*256 + b*16 + jl] + P.b_ih1[j];
        float xz = xgp[1*256 + b*16 + jl] + P.b_ih1[1024+j];
        float xn = xgp[2*256 + b*16 + jl] + P.b_ih1[2048+j];
        float r = sigm(xr + g1r + P.b_hh1[j]);
        float z = sigm(xz + g1z + P.b_hh1[1024+j]);
        float n = tanhf(xn + r*(g1n + P.b_hh1[2048+j]));
        float hnew = (1.f-z)*n + z*hprev;
        stfb(h1o + b*1024 + j, hnew);
        __bf16 hh2, ll2; split2(hnew, &hh2, &ll2);
        stsb(P.h1h + b*1024 + j, hh2);
        stsb(P.h1l + b*1024 + j, ll2);
        P.Hb[((size_t)t*16 + b)*1024 + j] = (__bf16)hnew;   // normal store (post-kernel consumer)
      }
    }
    barrier_dev(P.flags, blk, 3*t+4);
  }
}

// ---------- logits: BM=256, BN=128, 512 thr, bf16 B, LDS-staged (round-5) ----------
__global__ __launch_bounds__(512) void k_logits(
    const __bf16* __restrict__ Hb, const __bf16* __restrict__ Wb,
    const float* __restrict__ b_out, float* __restrict__ out)
{
  int c = blockIdx.x & 7, j = blockIdx.x >> 3;
  int x = j & 3, y = (j >> 2)*8 + c;
  if(y >= 250) return;
  int tm0 = x*256, tn0 = y*128;
  __shared__ __align__(16) __bf16 As[256][40];
  __shared__ __align__(16) __bf16 Bs[128][40];
  int tid = threadIdx.x;
  int lane = tid & 63, wave = tid >> 6;
  int wr = wave >> 1, wc = wave & 1;
  int qq = lane >> 4, rr = lane & 15;
  f32x4 acc[4][4] = {};
  int ar = tid >> 2, ak = (tid & 3) * 8;
  for(int k0=0;k0<1024;k0+=32){
    bf16x8 a0v = *(const bf16x8*)(Hb + (size_t)(tm0+ar)*1024     + k0 + ak);
    bf16x8 a1v = *(const bf16x8*)(Hb + (size_t)(tm0+ar+128)*1024 + k0 + ak);
    bf16x8 bv  = *(const bf16x8*)(Wb + (size_t)(tn0+ar)*1024     + k0 + ak);
    __syncthreads();
    *(bf16x8*)&As[ar][ak]     = a0v;
    *(bf16x8*)&As[ar+128][ak] = a1v;
    *(bf16x8*)&Bs[ar][ak]     = bv;
    __syncthreads();
    bf16x8 af[4], bfr[4];
    #pragma unroll
    for(int mi=0;mi<4;++mi) af[mi]  = *(const bf16x8*)&As[wr*64 + mi*16 + rr][qq*8];
    #pragma unroll
    for(int ni=0;ni<4;++ni) bfr[ni] = *(const bf16x8*)&Bs[wc*64 + ni*16 + rr][qq*8];
    #pragma unroll
    for(int mi=0;mi<4;++mi)
      #pragma unroll
      for(int ni=0;ni<4;++ni)
        acc[mi][ni] = MFMA16(af[mi], bfr[ni], acc[mi][ni], 0,0,0);
  }
  #pragma unroll
  for(int mi=0;mi<4;++mi)
    #pragma unroll
    for(int ni=0;ni<4;++ni)
      #pragma unroll
      for(int i=0;i<4;++i){
        int m = tm0 + wr*64 + mi*16 + qq*4 + i;
        int v = tn0 + wc*64 + ni*16 + rr;
        int bb = m & 15, tt = m >> 4;
        out[((size_t)bb*64 + tt)*32000 + v] = acc[mi][ni][i] + b_out[v];
      }
}

extern "C" void kernel_launch(void* const* d_in, const int* in_sizes, int n_in,
                              void* d_out, int out_size, void* d_ws, size_t ws_size,
                              hipStream_t stream){
  const int*   tgt    = (const int*)d_in[0];
  const float* hidden = (const float*)d_in[1];
  const float* enc    = (const float*)d_in[2];
  const float* emb    = (const float*)d_in[3];
  const float* Wq     = (const float*)d_in[4];
  const float* Wk     = (const float*)d_in[5];
  const float* v_att  = (const float*)d_in[6];
  const float* W_ih0  = (const float*)d_in[7];
  const float* W_hh0  = (const float*)d_in[8];
  const float* b_ih0  = (const float*)d_in[9];
  const float* b_hh0  = (const float*)d_in[10];
  const float* W_ih1  = (const float*)d_in[11];
  const float* W_hh1  = (const float*)d_in[12];
  const float* b_ih1  = (const float*)d_in[13];
  const float* b_hh1  = (const float*)d_in[14];
  const float* W_out  = (const float*)d_in[15];
  const float* b_out  = (const float*)d_in[16];
  float* out = (float*)d_out;

  float* ws = (float*)d_ws;
  size_t off = 0;
  auto alloc = [&](size_t n){ float* p = ws + off; off += n; return p; };
  float*  kp     = alloc((size_t)1024*1024);
  float*  GX0x   = alloc((size_t)1024*3072);
  float*  EW     = alloc((size_t)1024*3072);
  __bf16* Whh0p  = (__bf16*)alloc((size_t)3072*1024);
  __bf16* Whh1p  = (__bf16*)alloc((size_t)3072*1024);
  __bf16* Wih1p  = (__bf16*)alloc((size_t)3072*1024);
  __bf16* Wqp    = (__bf16*)alloc((size_t)1024*1024);
  float*  gh0    = alloc((size_t)16*3072);
  float*  gh1    = alloc((size_t)16*3072);
  float*  parts  = alloc((size_t)64*1024);
  float*  h0A    = alloc((size_t)16*1024);
  float*  h0B    = alloc((size_t)16*1024);
  float*  h1A    = alloc((size_t)16*1024);
  float*  h1B    = alloc((size_t)16*1024);
  __bf16* h0sh   = (__bf16*)alloc((size_t)8192);
  __bf16* h0sl   = (__bf16*)alloc((size_t)8192);
  __bf16* h1sh   = (__bf16*)alloc((size_t)8192);
  __bf16* h1sl   = (__bf16*)alloc((size_t)8192);
  float*  Hb_f   = alloc((size_t)512*1024);
  int*    flags  = (int*)alloc((size_t)256);
  __bf16* Hb     = (__bf16*)Hb_f;
  // aliases: emb_tok lives where Hb will go; WT where EW will go; Woutb
  // overlays kp..Wqp (dead after the recurrence; Hb/flags sit above 16.4M floats).
  float*  emb_tok = Hb_f;
  float*  WT      = EW;
  __bf16* Woutb   = (__bf16*)ws;          // 32000x1024 bf16 = 16.384M floats
  (void)ws_size; (void)in_sizes; (void)n_in; (void)out_size;

  // ---- setup ----
  k_gather<<<1024,256,0,stream>>>(tgt, emb, emb_tok);
  k_transpose<<<dim3(32,32),256,0,stream>>>(Wk, WT, 1024, 1024);
  k_gemm_s<<<dim3(8,16),256,0,stream>>>(enc,1024, WT,1024, nullptr, kp, 1024, 1024);
  k_gemm_s<<<dim3(8,48),256,0,stream>>>(emb_tok,512, W_ih0,1536, b_ih0, GX0x, 3072, 512);
  k_gemm_s<<<dim3(8,48),256,0,stream>>>(enc,1024, W_ih0+512,1536, nullptr, EW, 3072, 1024);
  k_pack_wT<<<64,256,0,stream>>>(Wq, 1024, Wqp);
  k_pack_w<<<192,256,0,stream>>>(W_hh0, Whh0p);
  k_pack_w<<<192,256,0,stream>>>(W_hh1, Whh1p);
  k_pack_w<<<192,256,0,stream>>>(W_ih1, Wih1p);
  k_split_h<<<128,256,0,stream>>>(hidden, h0sh, h0sl, h1sh, h1sl);
  k_init<<<1,256,0,stream>>>(flags);

  // ---- persistent recurrence (custom L2-preserving barriers, no grid.sync) ----
  RecP P;
  P.Whh1p = Whh1p; P.Wqp = Wqp; P.Wih1p = Wih1p; P.Whh0p = Whh0p;
  P.kp = kp; P.EW = EW; P.GX0x = GX0x; P.v_att = v_att;
  P.b_hh0 = b_hh0; P.b_ih1 = b_ih1; P.b_hh1 = b_hh1;
  P.hidden = hidden;
  P.h0h = h0sh; P.h0l = h0sl; P.h1h = h1sh; P.h1l = h1sl;
  P.gh0 = gh0; P.gh1 = gh1; P.parts = parts;
  P.h0A = h0A; P.h0B = h0B; P.h1A = h1A; P.h1B = h1B;
  P.Hb = Hb; P.flags = flags;
  void* args[] = { &P };
  hipLaunchCooperativeKernel((const void*)k_rec, dim3(256), dim3(512), args, 0, stream);

  // ---- deferred logits ----
  k_cvt16<<<16000,256,0,stream>>>(W_out, Woutb);
  k_logits<<<1024,512,0,stream>>>(Hb, Woutb, b_out, out);
}

// Round 9
// 3524.003 us; speedup vs baseline: 1.0609x; 1.0603x over previous
//
#include <hip/hip_runtime.h>
#include <hip/hip_cooperative_groups.h>
#include <hip/hip_bf16.h>
#include <math.h>

// V=32000 E=512 H=1024 A=1024 L=2 B=16 T=64 S=64
typedef __bf16 bf16x8 __attribute__((ext_vector_type(8)));
typedef float  f32x4  __attribute__((ext_vector_type(4)));

#define MFMA16 __builtin_amdgcn_mfma_f32_16x16x32_bf16
#define WAIT_VM0()   { asm volatile("s_waitcnt vmcnt(0)" ::: "memory");   __builtin_amdgcn_sched_barrier(0); }
#define WAIT_LGKM0() { asm volatile("s_waitcnt lgkmcnt(0)" ::: "memory"); __builtin_amdgcn_sched_barrier(0); }

__device__ __forceinline__ float sigm(float x){ return 1.0f/(1.0f+expf(-x)); }
__device__ __forceinline__ f32x4 ld4(const float* p){ return *(const f32x4*)p; }
__device__ __forceinline__ void split2(float x, __bf16* h, __bf16* l){
  __bf16 hh = (__bf16)x; *h = hh; *l = (__bf16)(x - (float)hh);
}

// ======== coherent (MALL) access helpers: sc0 sc1 ========
__device__ __forceinline__ bf16x8 ldx4b_bf(const __bf16* p){
  bf16x8 r;
  asm volatile("global_load_dwordx4 %0, %1, off sc0 sc1" : "=v"(r) : "v"(p) : "memory");
  return r;
}
__device__ __forceinline__ float ldfb(const float* p){
  float r;
  asm volatile("global_load_dword %0, %1, off sc0 sc1" : "=v"(r) : "v"(p) : "memory");
  return r;
}
__device__ __forceinline__ void stfb(float* p, float v){
  asm volatile("global_store_dword %0, %1, off sc0 sc1" :: "v"(p), "v"(v) : "memory");
}
__device__ __forceinline__ void stsb(__bf16* p, __bf16 v){
  unsigned int b = (unsigned int)__builtin_bit_cast(unsigned short, v);
  asm volatile("global_store_short %0, %1, off sc0 sc1" :: "v"(p), "v"(b) : "memory");
}

// ======== cheap L2-preserving grid barrier: one atomic + 1-dword poll ========
// Monotonic counter; thread 0 arrives via device-scope atomicAdd then polls a
// single dword with backoff. No fences, no cache invalidation, ~64B/poll.
__device__ __forceinline__ void barrier_dev(int* ctr, int target){
  WAIT_VM0();                      // all this block's bypass stores are globally visible
  __syncthreads();
  if(threadIdx.x == 0){
    atomicAdd(ctr, 1);             // device-scope by default on CDNA
    int v;
    do {
      __builtin_amdgcn_s_sleep(2);
      asm volatile("global_load_dword %0, %1, off sc0 sc1\n\ts_waitcnt vmcnt(0)"
                   : "=v"(v) : "v"(ctr) : "memory");
    } while(v < target);
  }
  __syncthreads();
}

// ---------- transpose fp32 ----------
__global__ __launch_bounds__(256) void k_transpose(const float* __restrict__ in,
                                                   float* __restrict__ out, int R, int C){
  __shared__ float tile[32][33];
  int c0 = blockIdx.x*32, r0 = blockIdx.y*32;
  int tx = threadIdx.x & 31, ty = threadIdx.x >> 5;
  for(int i=ty;i<32;i+=8) tile[i][tx] = in[(size_t)(r0+i)*C + c0+tx];
  __syncthreads();
  for(int i=ty;i<32;i+=8) out[(size_t)(c0+i)*R + r0+tx] = tile[tx][i];
}

// ---------- gather fp32 ----------
__global__ __launch_bounds__(256) void k_gather(const int* __restrict__ tgt,
                                                const float* __restrict__ emb,
                                                float* __restrict__ emb_tok){
  int m = blockIdx.x;            // m = t*16+b
  int t = m >> 4, b = m & 15;
  int row = tgt[b*64 + t];
  const float* src = emb + (size_t)row*512;
  float* dst = emb_tok + (size_t)m*512;
  for(int e=threadIdx.x;e<512;e+=256) dst[e] = src[e];
}

// ---------- setup GEMM (hi/lo MFMA, fp32-accurate) ----------
__global__ __launch_bounds__(256) void k_gemm_s(
    const float* __restrict__ A, int lda,
    const float* __restrict__ Bt, int ldb,
    const float* __restrict__ bias,
    float* __restrict__ C, int N, int K)
{
  __shared__ __align__(16) __bf16 Ash[128][40];
  __shared__ __align__(16) __bf16 Asl[128][40];
  __shared__ __align__(16) __bf16 Bsh[64][40];
  __shared__ __align__(16) __bf16 Bsl[64][40];
  int tid = threadIdx.x;
  int m0 = blockIdx.x*128, n0 = blockIdx.y*64;
  int lane = tid & 63, wave = tid >> 6;
  int wr = wave >> 1, wc = wave & 1;
  int qq = lane >> 4, rr = lane & 15;
  f32x4 acc[4][2] = {};
  int ar = tid >> 1, ak = (tid & 1)*16;
  int br = tid >> 2, bk = (tid & 3)*8;
  for(int k0=0;k0<K;k0+=32){
    const float* ap = A + (size_t)(m0+ar)*lda + k0 + ak;
    f32x4 a0 = ld4(ap), a1 = ld4(ap+4), a2 = ld4(ap+8), a3 = ld4(ap+12);
    const float* bp = Bt + (size_t)(n0+br)*ldb + k0 + bk;
    f32x4 b0 = ld4(bp), b1 = ld4(bp+4);
    __syncthreads();
    #pragma unroll
    for(int e=0;e<4;++e){
      split2(a0[e], &Ash[ar][ak+e],    &Asl[ar][ak+e]);
      split2(a1[e], &Ash[ar][ak+4+e],  &Asl[ar][ak+4+e]);
      split2(a2[e], &Ash[ar][ak+8+e],  &Asl[ar][ak+8+e]);
      split2(a3[e], &Ash[ar][ak+12+e], &Asl[ar][ak+12+e]);
      split2(b0[e], &Bsh[br][bk+e],    &Bsl[br][bk+e]);
      split2(b1[e], &Bsh[br][bk+4+e],  &Bsl[br][bk+4+e]);
    }
    __syncthreads();
    bf16x8 afh[4], afl[4], bfh[2], bfl[2];
    #pragma unroll
    for(int mi=0;mi<4;++mi){
      afh[mi] = *(const bf16x8*)&Ash[wr*64 + mi*16 + rr][qq*8];
      afl[mi] = *(const bf16x8*)&Asl[wr*64 + mi*16 + rr][qq*8];
    }
    #pragma unroll
    for(int ni=0;ni<2;++ni){
      bfh[ni] = *(const bf16x8*)&Bsh[wc*32 + ni*16 + rr][qq*8];
      bfl[ni] = *(const bf16x8*)&Bsl[wc*32 + ni*16 + rr][qq*8];
    }
    #pragma unroll
    for(int mi=0;mi<4;++mi)
      #pragma unroll
      for(int ni=0;ni<2;++ni){
        acc[mi][ni] = MFMA16(afh[mi], bfh[ni], acc[mi][ni], 0,0,0);
        acc[mi][ni] = MFMA16(afl[mi], bfh[ni], acc[mi][ni], 0,0,0);
        acc[mi][ni] = MFMA16(afh[mi], bfl[ni], acc[mi][ni], 0,0,0);
      }
  }
  #pragma unroll
  for(int mi=0;mi<4;++mi)
    #pragma unroll
    for(int ni=0;ni<2;++ni)
      #pragma unroll
      for(int i=0;i<4;++i){
        int m = m0 + wr*64 + mi*16 + qq*4 + i;
        int n = n0 + wc*32 + ni*16 + rr;
        C[(size_t)m*N + n] = acc[mi][ni][i] + (bias? bias[n] : 0.f);
      }
}

// ---------- pack W[J][1024] fp32 -> MFMA B-frag panels, bf16 HI only ----------
// Wp[(jt*32+kt)*512 + l*8 + e] = bf16( W[jt*16+(l&15)][kt*32+(l>>4)*8+e] )
__global__ __launch_bounds__(256) void k_pack_w(const float* __restrict__ W,
                                                __bf16* __restrict__ Wp){
  int jt = blockIdx.x, tid = threadIdx.x;
  #pragma unroll
  for(int it=0; it<8; ++it){
    int pos = it*256 + tid;           // 0..2047
    int kt = pos>>6, l = pos&63;
    const float* src = W + (size_t)(jt*16 + (l&15))*1024 + kt*32 + (l>>4)*8;
    f32x4 s0 = ld4(src), s1 = ld4(src+4);
    bf16x8 vh;
    #pragma unroll
    for(int e=0;e<4;++e){ vh[e] = (__bf16)s0[e]; vh[4+e] = (__bf16)s1[e]; }
    *(bf16x8*)(Wp + ((size_t)(jt*32 + kt))*512 + l*8) = vh;
  }
}

// ---------- pack, reading W transposed (hi only) ----------
__global__ __launch_bounds__(256) void k_pack_wT(const float* __restrict__ W, int ldw,
                                                 __bf16* __restrict__ Wp){
  int jt = blockIdx.x, tid = threadIdx.x;
  #pragma unroll
  for(int it=0; it<8; ++it){
    int pos = it*256 + tid;
    int kt = pos>>6, l = pos&63;
    int j = jt*16 + (l&15);
    int kbase = kt*32 + (l>>4)*8;
    bf16x8 vh;
    #pragma unroll
    for(int e=0;e<8;++e) vh[e] = (__bf16)W[(size_t)(kbase+e)*ldw + j];
    *(bf16x8*)(Wp + ((size_t)(jt*32 + kt))*512 + l*8) = vh;
  }
}

// ---------- split hidden -> h0/h1 bf16 hi/lo ----------
__global__ __launch_bounds__(256) void k_split_h(const float* __restrict__ hidden,
    __bf16* __restrict__ h0h, __bf16* __restrict__ h0l,
    __bf16* __restrict__ h1h, __bf16* __restrict__ h1l){
  int i = blockIdx.x*256 + threadIdx.x;
  float x = hidden[i];
  if(i < 16384) split2(x, &h0h[i], &h0l[i]);
  else { int j = i - 16384; split2(x, &h1h[j], &h1l[j]); }
}

// ---------- fp32 -> bf16 (x8) ----------
__global__ __launch_bounds__(256) void k_cvt16(const float* __restrict__ in,
                                               __bf16* __restrict__ out){
  int i = blockIdx.x*256 + threadIdx.x;
  const float* p = in + (size_t)i*8;
  f32x4 f0 = ld4(p), f1 = ld4(p+4);
  bf16x8 v;
  #pragma unroll
  for(int e=0;e<4;++e){ v[e] = (__bf16)f0[e]; v[4+e] = (__bf16)f1[e]; }
  *(bf16x8*)(out + (size_t)i*8) = v;
}

// ---------- zero barrier counter ----------
__global__ void k_init(int* ctr){ if(threadIdx.x==0) *ctr = 0; }

// ---------- gload_lds panel staging (normal cached path; stable tile -> L2-hot) ----------
// hi-only tile = 32 KB; wave w stages kt w*4..w*4+3 (4 KB, 4 issues).
__device__ __forceinline__ void stage_tile(const __bf16* __restrict__ Wp, int jt,
                                           char* stage, int w, int lane){
  const char* gsrc = (const char*)Wp + (size_t)jt*32768 + (size_t)w*4096 + lane*16;
  char* ldst = stage + w*4096;
  #pragma unroll
  for(int i=0;i<4;++i)
    __builtin_amdgcn_global_load_lds(
      (const __attribute__((address_space(1))) unsigned int*)(gsrc + i*1024),
      (__attribute__((address_space(3))) unsigned int*)(ldst + i*1024), 16, 0, 0);
}

// ---------- MFMA GEMV, W bf16-hi, h compensated: out = (ah+al)@Wh ----------
__device__ __forceinline__ void gemv_byp(const __bf16* hh, const __bf16* hl,
                                         const __bf16* __restrict__ Wp, int jt,
                                         char* stage, float* out, int ldo){
  int tid = threadIdx.x, lane = tid & 63, w = tid >> 6;
  const __bf16* Ah = hh + (lane&15)*1024 + (lane>>4)*8;
  const __bf16* Al = hl + (lane&15)*1024 + (lane>>4)*8;
  bf16x8 ah[4], al[4];
  #pragma unroll
  for(int kk=0;kk<4;++kk){
    ah[kk] = ldx4b_bf(Ah + (w*4+kk)*32);
    al[kk] = ldx4b_bf(Al + (w*4+kk)*32);
  }
  stage_tile(Wp, jt, stage, w, lane);
  WAIT_VM0();
  f32x4 acc = {0.f,0.f,0.f,0.f};
  #pragma unroll
  for(int kk=0;kk<4;++kk){
    bf16x8 bh = *(const bf16x8*)(stage + w*4096 + kk*1024 + lane*16);
    acc = MFMA16(ah[kk], bh, acc, 0,0,0);
    acc = MFMA16(al[kk], bh, acc, 0,0,0);
  }
  *(f32x4*)(stage + w*4096 + lane*16) = acc;
  __syncthreads();
  if(tid < 64){
    f32x4 s = *(const f32x4*)(stage + tid*16);
    #pragma unroll
    for(int k=1;k<8;++k) s += *(const f32x4*)(stage + k*4096 + tid*16);
    int j = jt*16 + (tid & 15);
    #pragma unroll
    for(int i=0;i<4;++i) stfb(out + (size_t)((tid>>4)*4 + i)*ldo + j, s[i]);
  }
  __syncthreads();
}

struct RecP {
  const __bf16 *Whh1p, *Wqp, *Wih1p, *Whh0p, *EWb;
  const float *kp, *GX0x, *v_att;
  const float *b_hh0, *b_ih1, *b_hh1;
  const float *hidden;
  __bf16 *h0h, *h0l, *h1h, *h1l;
  float *gh0, *gh1, *parts;
  float *h0A, *h0B, *h1A, *h1B;
  __bf16 *Hb;
  int *ctr;
};

// ---------- persistent recurrence: 256 blocks x 512 threads ----------
__global__ __launch_bounds__(512) void k_rec(RecP P){
  __shared__ __align__(16) char smem[36864];   // 32KB stage + 4KB aux
  int blk = blockIdx.x, tid = threadIdx.x;
  int lane = tid & 63, w = tid >> 6;

  // boot: gh0(0) = h0(0) @ Whh0^T  (blocks 64..255)
  if(blk >= 64) gemv_byp(P.h0h, P.h0l, P.Whh0p, blk-64, smem, P.gh0, 3072);
  barrier_dev(P.ctr, 256);

  for(int t=0;t<64;++t){
    const float* h0i = (t==0)? P.hidden           : ((t&1)? P.h0A : P.h0B);
    float*       h0o = (t&1)? P.h0B : P.h0A;
    const float* h1i = (t==0)? P.hidden + 16*1024 : ((t&1)? P.h1A : P.h1B);
    float*       h1o = (t&1)? P.h1B : P.h1A;

    // ===== P1: gh1 (192 blk) | q-slice + tanh-score partials (64 blk) =====
    if(blk < 192){
      gemv_byp(P.h1h, P.h1l, P.Whh1p, blk, smem, P.gh1, 3072);
    } else {
      int slice = blk - 192;
      const __bf16* Ah = P.h1h + (lane&15)*1024 + (lane>>4)*8;
      const __bf16* Al = P.h1l + (lane&15)*1024 + (lane>>4)*8;
      bf16x8 ah[4], al[4];
      #pragma unroll
      for(int kk=0;kk<4;++kk){
        ah[kk] = ldx4b_bf(Ah + (w*4+kk)*32);
        al[kk] = ldx4b_bf(Al + (w*4+kk)*32);
      }
      stage_tile(P.Wqp, slice, smem, w, lane);
      WAIT_VM0();
      f32x4 acc = {0.f,0.f,0.f,0.f};
      #pragma unroll
      for(int kk=0;kk<4;++kk){
        bf16x8 bh = *(const bf16x8*)(smem + w*4096 + kk*1024 + lane*16);
        acc = MFMA16(ah[kk], bh, acc, 0,0,0);
        acc = MFMA16(al[kk], bh, acc, 0,0,0);
      }
      *(f32x4*)(smem + w*4096 + lane*16) = acc;
      __syncthreads();
      float* qsp = (float*)(smem + 32768);      // qs[16 b][16 a_local]
      if(tid < 64){
        f32x4 s = *(const f32x4*)(smem + tid*16);
        #pragma unroll
        for(int k=1;k<8;++k) s += *(const f32x4*)(smem + k*4096 + tid*16);
        #pragma unroll
        for(int i=0;i<4;++i) qsp[((tid>>4)*4 + i)*16 + (tid&15)] = s[i];
      }
      __syncthreads();
      const float* vp = P.v_att + slice*16;
      f32x4 v0 = ld4(vp), v1 = ld4(vp+4), v2 = ld4(vp+8), v3 = ld4(vp+12);
      #pragma unroll
      for(int r=0;r<2;++r){
        int pair = r*512 + tid;          // b*64 + s
        int b = pair >> 6;
        const float* kpr = P.kp + (size_t)pair*1024 + slice*16;   // cached, L2-hot
        f32x4 c0 = ld4(kpr), c1 = ld4(kpr+4), c2 = ld4(kpr+8), c3 = ld4(kpr+12);
        const float* qb = qsp + b*16;
        float acc2 = 0.f;
        #pragma unroll
        for(int e=0;e<4;++e){
          acc2 += v0[e]*tanhf(qb[e]     + c0[e]);
          acc2 += v1[e]*tanhf(qb[4+e]   + c1[e]);
          acc2 += v2[e]*tanhf(qb[8+e]   + c2[e]);
          acc2 += v3[e]*tanhf(qb[12+e]  + c3[e]);
        }
        stfb(P.parts + (size_t)slice*1024 + pair, acc2);
      }
    }
    barrier_dev(P.ctr, 256*(3*t+2));

    // ===== P2: softmax + attn.EW + GRU0 -> h0n (all 256 blk) =====
    {
      float* ssum = (float*)smem;              // [256][2]
      float* scv  = (float*)(smem + 2048);     // [4][64]
      float* sden = (float*)(smem + 3072);     // [4]
      float* prt  = (float*)(smem + 3136);     // [8][4][16][3]
      int jt = blk >> 2, bq = blk & 3;
      {
        int hf = tid >> 8, p = tid & 255;
        int pair = bq*256 + p;
        const float* base = P.parts + (size_t)(hf*32)*1024 + pair;
        float v[32];
        #pragma unroll
        for(int k=0;k<32;++k) v[k] = ldfb(base + (size_t)k*1024);
        WAIT_VM0();
        float s = 0.f;
        #pragma unroll
        for(int k=0;k<32;++k) s += v[k];
        ssum[p*2 + hf] = s;
      }
      __syncthreads();
      if(tid < 256) scv[(tid>>6)*64 + (tid&63)] = expf(ssum[tid*2] + ssum[tid*2+1]);
      __syncthreads();
      if(tid < 4){
        float d = 0.f;
        #pragma unroll
        for(int s2=0;s2<64;++s2) d += scv[tid*64 + s2];
        sden[tid] = d;
      }
      __syncthreads();
      int bl = lane >> 4, jl = lane & 15;
      int b = bq*4 + bl, col = jt*16 + jl;
      float a0=0.f, a1=0.f, a2=0.f;
      const __bf16* ewp = P.EWb + ((size_t)(b*64 + w*8))*3072 + col;  // cached, L2-hot
      #pragma unroll
      for(int si=0; si<8; ++si){
        float e = scv[bl*64 + w*8 + si];
        const __bf16* r2 = ewp + (size_t)si*3072;
        a0 += e*(float)r2[0]; a1 += e*(float)r2[1024]; a2 += e*(float)r2[2048];
      }
      prt[((w*4 + bl)*16 + jl)*3 + 0] = a0;
      prt[((w*4 + bl)*16 + jl)*3 + 1] = a1;
      prt[((w*4 + bl)*16 + jl)*3 + 2] = a2;
      __syncthreads();
      if(tid < 64){
        int bl2 = tid >> 4, jl2 = tid & 15;
        int b2 = bq*4 + bl2, j = jt*16 + jl2;
        float xr=0.f, xz=0.f, xn=0.f;
        #pragma unroll
        for(int k=0;k<8;++k){
          xr += prt[((k*4 + bl2)*16 + jl2)*3 + 0];
          xz += prt[((k*4 + bl2)*16 + jl2)*3 + 1];
          xn += prt[((k*4 + bl2)*16 + jl2)*3 + 2];
        }
        float g0r = ldfb(P.gh0 + (size_t)b2*3072 + j);
        float g0z = ldfb(P.gh0 + (size_t)b2*3072 + 1024 + j);
        float g0n = ldfb(P.gh0 + (size_t)b2*3072 + 2048 + j);
        float hprev = ldfb(h0i + b2*1024 + j);
        WAIT_VM0();
        float inv = 1.0f / sden[bl2];
        const float* gx = P.GX0x + ((size_t)t*16 + b2)*3072 + j;   // includes b_ih0
        float r = sigm(xr*inv + gx[0]    + g0r + P.b_hh0[j]);
        float z = sigm(xz*inv + gx[1024] + g0z + P.b_hh0[1024+j]);
        float n = tanhf(xn*inv + gx[2048] + r*(g0n + P.b_hh0[2048+j]));
        float hnew = (1.f-z)*n + z*hprev;
        stfb(h0o + b2*1024 + j, hnew);
        __bf16 hh2, ll2; split2(hnew, &hh2, &ll2);
        stsb(P.h0h + b2*1024 + j, hh2);
        stsb(P.h0l + b2*1024 + j, ll2);
      }
    }
    barrier_dev(P.ctr, 256*(3*t+3));

    // ===== P3: h1n 3-gate (64 blk) | gh0(t+1) (192 blk) =====
    if(blk >= 64){
      gemv_byp(P.h0h, P.h0l, P.Whh0p, blk-64, smem, P.gh0, 3072);
    } else {
      const __bf16* Ah = P.h0h + (lane&15)*1024 + (lane>>4)*8;
      const __bf16* Al = P.h0l + (lane&15)*1024 + (lane>>4)*8;
      bf16x8 ah[4], al[4];
      #pragma unroll
      for(int kk=0;kk<4;++kk){
        ah[kk] = ldx4b_bf(Ah + (w*4+kk)*32);
        al[kk] = ldx4b_bf(Al + (w*4+kk)*32);
      }
      f32x4 accg[3];
      bf16x8 bh[4];
      stage_tile(P.Wih1p, 0*64 + blk, smem, w, lane);
      WAIT_VM0();
      #pragma unroll
      for(int g=0; g<3; ++g){
        if(g) WAIT_VM0();
        #pragma unroll
        for(int kk=0;kk<4;++kk)
          bh[kk] = *(const bf16x8*)(smem + w*4096 + kk*1024 + lane*16);
        if(g < 2){
          WAIT_LGKM0();                       // frags in regs; region reusable
          stage_tile(P.Wih1p, (g+1)*64 + blk, smem, w, lane);
        }
        f32x4 acc = {0.f,0.f,0.f,0.f};
        #pragma unroll
        for(int kk=0;kk<4;++kk){
          acc = MFMA16(ah[kk], bh[kk], acc, 0,0,0);
          acc = MFMA16(al[kk], bh[kk], acc, 0,0,0);
        }
        accg[g] = acc;
      }
      #pragma unroll
      for(int g=0; g<3; ++g)
        *(f32x4*)(smem + w*4096 + g*1024 + lane*16) = accg[g];
      __syncthreads();
      float* xgp = (float*)(smem + 32768);     // xg[3][16][16] = 3KB
      if(tid < 192){
        int g = tid >> 6, tt = tid & 63;
        f32x4 s = *(const f32x4*)(smem + g*1024 + tt*16);
        #pragma unroll
        for(int k=1;k<8;++k) s += *(const f32x4*)(smem + k*4096 + g*1024 + tt*16);
        #pragma unroll
        for(int i=0;i<4;++i) xgp[g*256 + ((tt>>4)*4 + i)*16 + (tt&15)] = s[i];
      }
      __syncthreads();
      if(tid < 256){
        int b = tid >> 4, jl = tid & 15, j = blk*16 + jl;
        float g1r = ldfb(P.gh1 + (size_t)b*3072 + j);
        float g1z = ldfb(P.gh1 + (size_t)b*3072 + 1024 + j);
        float g1n = ldfb(P.gh1 + (size_t)b*3072 + 2048 + j);
        float hprev = ldfb(h1i + b*1024 + j);
        WAIT_VM0();
        float xr = xgp[0*256 + b*16 + jl] + P.b_ih1[j];
        float xz = xgp[1*256 + b*16 + jl] + P.b_ih1[1024+j];
        float xn = xgp[2*256 + b*16 + jl] + P.b_ih1[2048+j];
        float r = sigm(xr + g1r + P.b_hh1[j]);
        float z = sigm(xz + g1z + P.b_hh1[1024+j]);
        float n = tanhf(xn + r*(g1n + P.b_hh1[2048+j]));
        float hnew = (1.f-z)*n + z*hprev;
        stfb(h1o + b*1024 + j, hnew);
        __bf16 hh2, ll2; split2(hnew, &hh2, &ll2);
        stsb(P.h1h + b*1024 + j, hh2);
        stsb(P.h1l + b*1024 + j, ll2);
        P.Hb[((size_t)t*16 + b)*1024 + j] = (__bf16)hnew;   // normal store (post-kernel consumer)
      }
    }
    barrier_dev(P.ctr, 256*(3*t+4));
  }
}

// ---------- logits: BM=256, BN=128, 512 thr, bf16 B, LDS-staged ----------
__global__ __launch_bounds__(512) void k_logits(
    const __bf16* __restrict__ Hb, const __bf16* __restrict__ Wb,
    const float* __restrict__ b_out, float* __restrict__ out)
{
  int c = blockIdx.x & 7, j = blockIdx.x >> 3;
  int x = j & 3, y = (j >> 2)*8 + c;
  if(y >= 250) return;
  int tm0 = x*256, tn0 = y*128;
  __shared__ __align__(16) __bf16 As[256][40];
  __shared__ __align__(16) __bf16 Bs[128][40];
  int tid = threadIdx.x;
  int lane = tid & 63, wave = tid >> 6;
  int wr = wave >> 1, wc = wave & 1;
  int qq = lane >> 4, rr = lane & 15;
  f32x4 acc[4][4] = {};
  int ar = tid >> 2, ak = (tid & 3) * 8;
  for(int k0=0;k0<1024;k0+=32){
    bf16x8 a0v = *(const bf16x8*)(Hb + (size_t)(tm0+ar)*1024     + k0 + ak);
    bf16x8 a1v = *(const bf16x8*)(Hb + (size_t)(tm0+ar+128)*1024 + k0 + ak);
    bf16x8 bv  = *(const bf16x8*)(Wb + (size_t)(tn0+ar)*1024     + k0 + ak);
    __syncthreads();
    *(bf16x8*)&As[ar][ak]     = a0v;
    *(bf16x8*)&As[ar+128][ak] = a1v;
    *(bf16x8*)&Bs[ar][ak]     = bv;
    __syncthreads();
    bf16x8 af[4], bfr[4];
    #pragma unroll
    for(int mi=0;mi<4;++mi) af[mi]  = *(const bf16x8*)&As[wr*64 + mi*16 + rr][qq*8];
    #pragma unroll
    for(int ni=0;ni<4;++ni) bfr[ni] = *(const bf16x8*)&Bs[wc*64 + ni*16 + rr][qq*8];
    #pragma unroll
    for(int mi=0;mi<4;++mi)
      #pragma unroll
      for(int ni=0;ni<4;++ni)
        acc[mi][ni] = MFMA16(af[mi], bfr[ni], acc[mi][ni], 0,0,0);
  }
  #pragma unroll
  for(int mi=0;mi<4;++mi)
    #pragma unroll
    for(int ni=0;ni<4;++ni)
      #pragma unroll
      for(int i=0;i<4;++i){
        int m = tm0 + wr*64 + mi*16 + qq*4 + i;
        int v = tn0 + wc*64 + ni*16 + rr;
        int bb = m & 15, tt = m >> 4;
        out[((size_t)bb*64 + tt)*32000 + v] = acc[mi][ni][i] + b_out[v];
      }
}

extern "C" void kernel_launch(void* const* d_in, const int* in_sizes, int n_in,
                              void* d_out, int out_size, void* d_ws, size_t ws_size,
                              hipStream_t stream){
  const int*   tgt    = (const int*)d_in[0];
  const float* hidden = (const float*)d_in[1];
  const float* enc    = (const float*)d_in[2];
  const float* emb    = (const float*)d_in[3];
  const float* Wq     = (const float*)d_in[4];
  const float* Wk     = (const float*)d_in[5];
  const float* v_att  = (const float*)d_in[6];
  const float* W_ih0  = (const float*)d_in[7];
  const float* W_hh0  = (const float*)d_in[8];
  const float* b_ih0  = (const float*)d_in[9];
  const float* b_hh0  = (const float*)d_in[10];
  const float* W_ih1  = (const float*)d_in[11];
  const float* W_hh1  = (const float*)d_in[12];
  const float* b_ih1  = (const float*)d_in[13];
  const float* b_hh1  = (const float*)d_in[14];
  const float* W_out  = (const float*)d_in[15];
  const float* b_out  = (const float*)d_in[16];
  float* out = (float*)d_out;

  float* ws = (float*)d_ws;
  size_t off = 0;
  auto alloc = [&](size_t n){ float* p = ws + off; off += n; return p; };
  float*  kp     = alloc((size_t)1024*1024);          // fp32, L2-hot per attn block
  float*  GX0x   = alloc((size_t)1024*3072);          // fp32 (+b_ih0)
  float*  EWf    = alloc((size_t)1024*3072);          // fp32 (setup only)
  __bf16* EWb    = (__bf16*)alloc((size_t)1572864);   // 1024x3072 bf16
  __bf16* Whh0p  = (__bf16*)alloc((size_t)1572864);   // hi-only panels
  __bf16* Whh1p  = (__bf16*)alloc((size_t)1572864);
  __bf16* Wih1p  = (__bf16*)alloc((size_t)1572864);
  __bf16* Wqp    = (__bf16*)alloc((size_t)524288);
  float*  gh0    = alloc((size_t)16*3072);
  float*  gh1    = alloc((size_t)16*3072);
  float*  parts  = alloc((size_t)64*1024);
  float*  h0A    = alloc((size_t)16*1024);
  float*  h0B    = alloc((size_t)16*1024);
  float*  h1A    = alloc((size_t)16*1024);
  float*  h1B    = alloc((size_t)16*1024);
  __bf16* h0sh   = (__bf16*)alloc((size_t)8192);
  __bf16* h0sl   = (__bf16*)alloc((size_t)8192);
  __bf16* h1sh   = (__bf16*)alloc((size_t)8192);
  __bf16* h1sl   = (__bf16*)alloc((size_t)8192);
  // Hb placed at a fixed offset >= 16M floats so Woutb ([0,16M) floats) never overlaps
  float*  Hb_f   = ws + 16777216;
  __bf16* Hb     = (__bf16*)Hb_f;
  int*    ctr    = (int*)(ws + 16777216 + 524288);
  float*  emb_tok = Hb_f;                 // setup-only alias (dead before k_rec)
  float*  WT      = (float*)EWb;          // Wk^T scratch; overwritten later by EWb cvt
  __bf16* Woutb   = (__bf16*)ws;          // 32000x1024 bf16 = 16M floats
  (void)ws_size; (void)in_sizes; (void)n_in; (void)out_size; (void)off;

  // ---- setup ----
  k_gather<<<1024,256,0,stream>>>(tgt, emb, emb_tok);
  k_transpose<<<dim3(32,32),256,0,stream>>>(Wk, WT, 1024, 1024);
  k_gemm_s<<<dim3(8,16),256,0,stream>>>(enc,1024, WT,1024, nullptr, kp, 1024, 1024);
  k_gemm_s<<<dim3(8,48),256,0,stream>>>(emb_tok,512, W_ih0,1536, b_ih0, GX0x, 3072, 512);
  k_gemm_s<<<dim3(8,48),256,0,stream>>>(enc,1024, W_ih0+512,1536, nullptr, EWf, 3072, 1024);
  k_cvt16<<<1536,256,0,stream>>>(EWf, EWb);          // overwrites WT (dead)
  k_pack_wT<<<64,256,0,stream>>>(Wq, 1024, Wqp);
  k_pack_w<<<192,256,0,stream>>>(W_hh0, Whh0p);
  k_pack_w<<<192,256,0,stream>>>(W_hh1, Whh1p);
  k_pack_w<<<192,256,0,stream>>>(W_ih1, Wih1p);
  k_split_h<<<128,256,0,stream>>>(hidden, h0sh, h0sl, h1sh, h1sl);
  k_init<<<1,64,0,stream>>>(ctr);

  // ---- persistent recurrence (atomic-counter barrier, L2-preserving) ----
  RecP P;
  P.Whh1p = Whh1p; P.Wqp = Wqp; P.Wih1p = Wih1p; P.Whh0p = Whh0p; P.EWb = EWb;
  P.kp = kp; P.GX0x = GX0x; P.v_att = v_att;
  P.b_hh0 = b_hh0; P.b_ih1 = b_ih1; P.b_hh1 = b_hh1;
  P.hidden = hidden;
  P.h0h = h0sh; P.h0l = h0sl; P.h1h = h1sh; P.h1l = h1sl;
  P.gh0 = gh0; P.gh1 = gh1; P.parts = parts;
  P.h0A = h0A; P.h0B = h0B; P.h1A = h1A; P.h1B = h1B;
  P.Hb = Hb; P.ctr = ctr;
  void* args[] = { &P };
  hipLaunchCooperativeKernel((const void*)k_rec, dim3(256), dim3(512), args, 0, stream);

  // ---- deferred logits ----
  k_cvt16<<<16000,256,0,stream>>>(W_out, Woutb);
  k_logits<<<1024,512,0,stream>>>(Hb, Woutb, b_out, out);
}